// Round 1
// baseline (1223.835 us; speedup 1.0000x reference)
//
#include <hip/hip_runtime.h>
#include <math.h>

#define NN 20000
#define EF 720000

// ---------------------------------------------------------------- transpose prep
__global__ __launch_bounds__(256) void k_transpose(
    const float* __restrict__ mw1, const float* __restrict__ mw2, const float* __restrict__ mw3,
    const float* __restrict__ hw1, const float* __restrict__ hw2, const float* __restrict__ hw3,
    const float* __restrict__ we,
    float* __restrict__ mw1T, float* __restrict__ mw2T, float* __restrict__ mw3T,
    float* __restrict__ hw1T, float* __restrict__ hw2T, float* __restrict__ hw3T,
    float* __restrict__ weT)
{
    int t = blockIdx.x * 256 + threadIdx.x;
    if (t < 1344) { int c = t / 21, a = t % 21; mw1T[t] = mw1[a * 64 + c]; return; }
    t -= 1344;
    if (t < 4096) { int c = t / 64, k = t % 64; mw2T[t] = mw2[k * 64 + c]; return; }
    t -= 4096;
    if (t < 4096) { int c = t / 64, k = t % 64; mw3T[t] = mw3[k * 64 + c]; return; }
    t -= 4096;
    if (t < 4096) { int c = t / 64, k = t % 64; hw1T[t] = hw1[k * 64 + c]; return; }
    t -= 4096;
    if (t < 4096) { int c = t / 64, k = t % 64; hw2T[t] = hw2[k * 64 + c]; return; }
    t -= 4096;
    if (t < 1280) { int c = t / 64, k = t % 64; hw3T[t] = hw3[k * 20 + c]; return; }
    t -= 1280;
    if (t < 10752) { int cf = t / 84, a = t % 84; weT[t] = we[a * 128 + cf]; return; }
}

// ---------------------------------------------------------------- degree count
__global__ __launch_bounds__(256) void k_count(
    const int* __restrict__ dst, const float* __restrict__ mask, int* __restrict__ cnt)
{
    int e = blockIdx.x * 256 + threadIdx.x;
    if (e < EF && mask[e] > 0.f) atomicAdd(&cnt[dst[e]], 1);
}

// ---------------------------------------------------------------- exclusive scan (single block)
__global__ __launch_bounds__(1024) void k_scan(const int* __restrict__ cnt, int* __restrict__ row_off)
{
    __shared__ int buf[1024];
    __shared__ int carry;
    int t = threadIdx.x;
    if (t == 0) { carry = 0; row_off[0] = 0; }
    __syncthreads();
    for (int base = 0; base < NN; base += 1024) {
        int i = base + t;
        int v = (i < NN) ? cnt[i] : 0;
        buf[t] = v;
        __syncthreads();
        for (int off = 1; off < 1024; off <<= 1) {
            int add = (t >= off) ? buf[t - off] : 0;
            __syncthreads();
            buf[t] += add;
            __syncthreads();
        }
        int incl = buf[t] + carry;
        if (i < NN) row_off[i + 1] = incl;
        __syncthreads();
        if (t == 1023) carry = incl;
        __syncthreads();
    }
}

// ---------------------------------------------------------------- CSR scatter
__global__ __launch_bounds__(256) void k_scatter(
    const int* __restrict__ dst, const float* __restrict__ mask,
    const int* __restrict__ row_off, int* __restrict__ cnt2, int* __restrict__ eidx)
{
    int e = blockIdx.x * 256 + threadIdx.x;
    if (e < EF && mask[e] > 0.f) {
        int d = dst[e];
        int p = atomicAdd(&cnt2[d], 1);
        eidx[row_off[d] + p] = e;
    }
}

// ---------------------------------------------------------------- node features + projections + qwe
__global__ __launch_bounds__(256) void k_node(
    const float* __restrict__ angle, const float* __restrict__ mol, const float* __restrict__ gen,
    const int* __restrict__ cnt,
    const float* __restrict__ wq, const float* __restrict__ bq,
    const float* __restrict__ wk, const float* __restrict__ bk,
    const float* __restrict__ wv, const float* __restrict__ bv,
    const float* __restrict__ wskip, const float* __restrict__ bskip,
    const float* __restrict__ weT,
    float* __restrict__ selff, float* __restrict__ qf, float* __restrict__ kf,
    float* __restrict__ vf, float* __restrict__ skipf, float* __restrict__ qwe)
{
    __shared__ float qlds[4 * 128];
    int wid = threadIdx.x >> 6, lane = threadIdx.x & 63;
    int n = blockIdx.x * 4 + wid;

    float an = angle[n];
    float sv, cv; sincosf(an, &sv, &cv);
    float degf = (float)cnt[n];
    float sf[20];
    sf[0] = sv; sf[1] = cv;
#pragma unroll
    for (int j = 0; j < 16; j++) sf[2 + j] = mol[n * 16 + j];
    sf[18] = gen[n];
    sf[19] = degf;

    float sval = (lane == 0) ? sv : (lane == 1) ? cv :
                 (lane < 18) ? mol[n * 16 + (lane - 2)] :
                 (lane == 18) ? gen[n] : degf;
    if (lane < 20) selff[n * 20 + lane] = sval;

    float q0 = bq[lane], q1 = bq[64 + lane];
    float k0 = bk[lane], k1 = bk[64 + lane];
    float v0 = bv[lane], v1 = bv[64 + lane];
    float sk = bskip[lane];
#pragma unroll
    for (int a = 0; a < 20; a++) {
        float s = sf[a];
        q0 += s * wq[a * 128 + lane];      q1 += s * wq[a * 128 + 64 + lane];
        k0 += s * wk[a * 128 + lane];      k1 += s * wk[a * 128 + 64 + lane];
        v0 += s * wv[a * 128 + lane];      v1 += s * wv[a * 128 + 64 + lane];
        sk += s * wskip[a * 64 + lane];
    }
    qf[n * 128 + lane] = q0; qf[n * 128 + 64 + lane] = q1;
    kf[n * 128 + lane] = k0; kf[n * 128 + 64 + lane] = k1;
    vf[n * 128 + lane] = v0; vf[n * 128 + 64 + lane] = v1;
    skipf[n * 64 + lane] = sk;
    qlds[wid * 128 + lane] = q0; qlds[wid * 128 + 64 + lane] = q1;
    __syncthreads();

    // qwe[n][h][a] = sum_c q[h][c] * we[a][h*64+c]  (weT[cf][a] layout => coalesced over a)
#pragma unroll
    for (int r = 0; r < 3; r++) {
        int o = r * 64 + lane;
        if (o < 168) {
            int h = (o >= 84) ? 1 : 0;
            int a = o - 84 * h;
            float acc = 0.f, acc2 = 0.f;
#pragma unroll
            for (int c = 0; c < 64; c += 2) {
                acc  += qlds[wid * 128 + h * 64 + c]     * weT[(h * 64 + c) * 84 + a];
                acc2 += qlds[wid * 128 + h * 64 + c + 1] * weT[(h * 64 + c + 1) * 84 + a];
            }
            qwe[n * 168 + o] = acc + acc2;
        }
    }
}

// ---------------------------------------------------------------- edge MLP -> msg  (thread per edge)
__global__ __launch_bounds__(64) void k_edge_mlp(
    const float* __restrict__ x, const float* __restrict__ angle, const float* __restrict__ mol,
    const int* __restrict__ src, const int* __restrict__ dst,
    const float* __restrict__ mw1T, const float* __restrict__ mb1,
    const float* __restrict__ mw2T, const float* __restrict__ mb2,
    const float* __restrict__ mw3T, const float* __restrict__ mb3,
    float* __restrict__ msg)
{
    __shared__ float hl[64 * 65];
    int lane = threadIdx.x;
    int e0 = blockIdx.x * 64;
    int e = e0 + lane;

    int s = src[e], d = dst[e];
    float dx = x[s * 2] - x[d * 2];
    float dy = x[s * 2 + 1] - x[d * 2 + 1];
    float r = sqrtf(fmaxf(dx * dx + dy * dy, 1e-12f));
    float da = angle[s] - angle[d];
    float sv, cv; sincosf(da, &sv, &cv);
    float rel[21];
    rel[0] = dx; rel[1] = dy; rel[2] = r; rel[3] = sv; rel[4] = cv;
#pragma unroll
    for (int j = 0; j < 16; j++) rel[5 + j] = mol[s * 16 + j] - mol[d * 16 + j];

    // stage 1: 21 -> 64
    for (int c = 0; c < 64; c++) {
        float a0 = mb1[c], a1 = 0.f, a2 = 0.f;
#pragma unroll
        for (int a = 0; a < 21; a += 3) {
            a0 += rel[a] * mw1T[c * 21 + a];
            if (a + 1 < 21) a1 += rel[a + 1] * mw1T[c * 21 + a + 1];
            if (a + 2 < 21) a2 += rel[a + 2] * mw1T[c * 21 + a + 2];
        }
        hl[c * 65 + lane] = fmaxf(a0 + a1 + a2, 0.f);
    }
    float h[64];
#pragma unroll
    for (int k = 0; k < 64; k++) h[k] = hl[k * 65 + lane];

    // stage 2: 64 -> 64
    for (int c = 0; c < 64; c++) {
        float a0 = mb2[c], a1 = 0.f, a2 = 0.f, a3 = 0.f;
#pragma unroll
        for (int k = 0; k < 64; k += 4) {
            a0 += h[k]     * mw2T[c * 64 + k];
            a1 += h[k + 1] * mw2T[c * 64 + k + 1];
            a2 += h[k + 2] * mw2T[c * 64 + k + 2];
            a3 += h[k + 3] * mw2T[c * 64 + k + 3];
        }
        hl[c * 65 + lane] = fmaxf((a0 + a1) + (a2 + a3), 0.f);
    }
#pragma unroll
    for (int k = 0; k < 64; k++) h[k] = hl[k * 65 + lane];

    // stage 3: 64 -> 64
    for (int c = 0; c < 64; c++) {
        float a0 = mb3[c], a1 = 0.f, a2 = 0.f, a3 = 0.f;
#pragma unroll
        for (int k = 0; k < 64; k += 4) {
            a0 += h[k]     * mw3T[c * 64 + k];
            a1 += h[k + 1] * mw3T[c * 64 + k + 1];
            a2 += h[k + 2] * mw3T[c * 64 + k + 2];
            a3 += h[k + 3] * mw3T[c * 64 + k + 3];
        }
        hl[c * 65 + lane] = fmaxf((a0 + a1) + (a2 + a3), 0.f);
    }
    __syncthreads();  // cross-lane transpose read below

    // transpose store: msg[e0+rr][lane] = h3[lane] of edge rr
#pragma unroll 4
    for (int rr = 0; rr < 64; rr++) {
        msg[(size_t)(e0 + rr) * 64 + lane] = hl[lane * 65 + rr];
    }
}

// ---------------------------------------------------------------- attention aggregate (wave per node)
__global__ __launch_bounds__(256) void k_attn(
    const int* __restrict__ row_off, const int* __restrict__ eidx, const int* __restrict__ src,
    const float* __restrict__ msg,
    const float* __restrict__ qf, const float* __restrict__ kf, const float* __restrict__ vf,
    const float* __restrict__ qwe, const float* __restrict__ selff, const float* __restrict__ skipf,
    const float* __restrict__ we,
    float* __restrict__ outb)
{
    __shared__ float we_lds[84 * 128];
    __shared__ float wm[4 * 128];
    int tid = threadIdx.x, wid = tid >> 6, lane = tid & 63;
    for (int i = tid; i < 84 * 128; i += 256) we_lds[i] = we[i];
    __syncthreads();

    int n = blockIdx.x * 4 + wid;
    float q0 = qf[n * 128 + lane], q1 = qf[n * 128 + 64 + lane];
    float qm0 = qwe[n * 168 + lane], qm1 = qwe[n * 168 + 84 + lane];
    float sf[20];
#pragma unroll
    for (int j = 0; j < 20; j++) sf[j] = selff[n * 20 + j];
    float a00 = 0.f, a01 = 0.f;
#pragma unroll
    for (int j = 0; j < 20; j++) {
        a00 += sf[j] * qwe[n * 168 + 64 + j];
        a01 += sf[j] * qwe[n * 168 + 84 + 64 + j];
    }

    int r0 = row_off[n], r1 = row_off[n + 1];
    float S0 = 0.f, S1 = 0.f, Wv0 = 0.f, Wv1 = 0.f, Wm0 = 0.f, Wm1 = 0.f;
    for (int i = r0; i < r1; i++) {
        int eid = eidx[i];
        int s = src[eid];
        float mc = msg[(size_t)eid * 64 + lane];
        float k0 = kf[s * 128 + lane], k1 = kf[s * 128 + 64 + lane];
        float v0 = vf[s * 128 + lane], v1 = vf[s * 128 + 64 + lane];
        float t0 = q0 * k0 + mc * qm0;
        float t1 = q1 * k1 + mc * qm1;
#pragma unroll
        for (int mk = 1; mk < 64; mk <<= 1) {
            t0 += __shfl_xor(t0, mk, 64);
            t1 += __shfl_xor(t1, mk, 64);
        }
        float al0 = (t0 + a00) * 0.125f;
        float al1 = (t1 + a01) * 0.125f;
        float w0 = __expf(al0), w1 = __expf(al1);
        S0 += w0; S1 += w1;
        Wv0 += w0 * v0; Wv1 += w1 * v1;
        Wm0 += w0 * mc; Wm1 += w1 * mc;
    }
    wm[wid * 128 + lane] = Wm0;
    wm[wid * 128 + 64 + lane] = Wm1;
    __syncthreads();

    // epilogue: out_h[c] = (Wv_h[c] + sum_a Wattr_h[a] we[a][h*64+c]) / (S_h + 1e-16)
    float acc0 = 0.f, acc1 = 0.f;
    for (int a = 0; a < 64; a += 2) {
        float wma0 = wm[wid * 128 + a],     wmb0 = wm[wid * 128 + 64 + a];
        float wma1 = wm[wid * 128 + a + 1], wmb1 = wm[wid * 128 + 64 + a + 1];
        acc0 += wma0 * we_lds[a * 128 + lane]        + wma1 * we_lds[(a + 1) * 128 + lane];
        acc1 += wmb0 * we_lds[a * 128 + 64 + lane]   + wmb1 * we_lds[(a + 1) * 128 + 64 + lane];
    }
#pragma unroll
    for (int j = 0; j < 20; j++) {
        acc0 += S0 * sf[j] * we_lds[(64 + j) * 128 + lane];
        acc1 += S1 * sf[j] * we_lds[(64 + j) * 128 + 64 + lane];
    }
    float o0 = (Wv0 + acc0) / (S0 + 1e-16f);
    float o1 = (Wv1 + acc1) / (S1 + 1e-16f);
    outb[n * 64 + lane] = 0.5f * (o0 + o1) + skipf[n * 64 + lane];
}

// ---------------------------------------------------------------- final MLP + split outputs (thread per node)
__global__ __launch_bounds__(64) void k_final(
    const float* __restrict__ outb,
    const float* __restrict__ hw1T, const float* __restrict__ hb1,
    const float* __restrict__ hw2T, const float* __restrict__ hb2,
    const float* __restrict__ hw3T, const float* __restrict__ hb3,
    float* __restrict__ out)
{
    __shared__ float ul[64 * 65];
    int lane = threadIdx.x;
    int n = blockIdx.x * 64 + lane;
    bool ok = (n < NN);
    int nn = ok ? n : (NN - 1);

    float h[64];
#pragma unroll
    for (int k = 0; k < 64; k++) h[k] = outb[nn * 64 + k];

    for (int c = 0; c < 64; c++) {
        float a0 = hb1[c], a1 = 0.f, a2 = 0.f, a3 = 0.f;
#pragma unroll
        for (int k = 0; k < 64; k += 4) {
            a0 += h[k]     * hw1T[c * 64 + k];
            a1 += h[k + 1] * hw1T[c * 64 + k + 1];
            a2 += h[k + 2] * hw1T[c * 64 + k + 2];
            a3 += h[k + 3] * hw1T[c * 64 + k + 3];
        }
        ul[c * 65 + lane] = fmaxf((a0 + a1) + (a2 + a3), 0.f);
    }
#pragma unroll
    for (int k = 0; k < 64; k++) h[k] = ul[k * 65 + lane];

    for (int c = 0; c < 64; c++) {
        float a0 = hb2[c], a1 = 0.f, a2 = 0.f, a3 = 0.f;
#pragma unroll
        for (int k = 0; k < 64; k += 4) {
            a0 += h[k]     * hw2T[c * 64 + k];
            a1 += h[k + 1] * hw2T[c * 64 + k + 1];
            a2 += h[k + 2] * hw2T[c * 64 + k + 2];
            a3 += h[k + 3] * hw2T[c * 64 + k + 3];
        }
        ul[c * 65 + lane] = fmaxf((a0 + a1) + (a2 + a3), 0.f);
    }
#pragma unroll
    for (int k = 0; k < 64; k++) h[k] = ul[k * 65 + lane];

    for (int c = 0; c < 20; c++) {
        float a0 = hb3[c], a1 = 0.f, a2 = 0.f, a3 = 0.f;
#pragma unroll
        for (int k = 0; k < 64; k += 4) {
            a0 += h[k]     * hw3T[c * 64 + k];
            a1 += h[k + 1] * hw3T[c * 64 + k + 1];
            a2 += h[k + 2] * hw3T[c * 64 + k + 2];
            a3 += h[k + 3] * hw3T[c * 64 + k + 3];
        }
        float upd = (a0 + a1) + (a2 + a3);
        if (ok) {
            if (c < 2)       out[n * 2 + c] = upd;
            else if (c == 2) out[2 * NN + n] = upd;
            else if (c < 19) out[3 * NN + n * 16 + (c - 3)] = upd;
            else             out[19 * NN + n] = upd;
        }
    }
}

// ---------------------------------------------------------------- launch
extern "C" void kernel_launch(void* const* d_in, const int* in_sizes, int n_in,
                              void* d_out, int out_size, void* d_ws, size_t ws_size,
                              hipStream_t stream)
{
    const float* x      = (const float*)d_in[0];
    const float* angle  = (const float*)d_in[1];
    const float* mol    = (const float*)d_in[2];
    const float* gen    = (const float*)d_in[3];
    const int*   src    = (const int*)d_in[4];
    const int*   dst    = (const int*)d_in[5];
    const float* mask   = (const float*)d_in[6];
    const float* mw1    = (const float*)d_in[7];
    const float* mb1    = (const float*)d_in[8];
    const float* mw2    = (const float*)d_in[9];
    const float* mb2    = (const float*)d_in[10];
    const float* mw3    = (const float*)d_in[11];
    const float* mb3    = (const float*)d_in[12];
    const float* wq     = (const float*)d_in[13];
    const float* bq     = (const float*)d_in[14];
    const float* wk     = (const float*)d_in[15];
    const float* bk     = (const float*)d_in[16];
    const float* wv     = (const float*)d_in[17];
    const float* bv     = (const float*)d_in[18];
    const float* we     = (const float*)d_in[19];
    const float* wskip  = (const float*)d_in[20];
    const float* bskip  = (const float*)d_in[21];
    const float* hw1    = (const float*)d_in[22];
    const float* hb1    = (const float*)d_in[23];
    const float* hw2    = (const float*)d_in[24];
    const float* hb2    = (const float*)d_in[25];
    const float* hw3    = (const float*)d_in[26];
    const float* hb3    = (const float*)d_in[27];
    float* out = (float*)d_out;

    char* p = (char*)d_ws;
    auto alloc = [&](size_t bytes) -> void* {
        void* r = (void*)p;
        p += (bytes + 255) & ~(size_t)255;
        return r;
    };
    int* cnt      = (int*)alloc(NN * 4);
    int* cnt2     = (int*)alloc(NN * 4);
    int* row_off  = (int*)alloc((NN + 1) * 4);
    int* eidx     = (int*)alloc((size_t)EF * 4);
    float* selff  = (float*)alloc((size_t)NN * 20 * 4);
    float* qf     = (float*)alloc((size_t)NN * 128 * 4);
    float* kf     = (float*)alloc((size_t)NN * 128 * 4);
    float* vf     = (float*)alloc((size_t)NN * 128 * 4);
    float* skipf  = (float*)alloc((size_t)NN * 64 * 4);
    float* qwe    = (float*)alloc((size_t)NN * 168 * 4);
    float* outb   = (float*)alloc((size_t)NN * 64 * 4);
    float* mw1T   = (float*)alloc(1344 * 4);
    float* mw2T   = (float*)alloc(4096 * 4);
    float* mw3T   = (float*)alloc(4096 * 4);
    float* hw1T   = (float*)alloc(4096 * 4);
    float* hw2T   = (float*)alloc(4096 * 4);
    float* hw3T   = (float*)alloc(1280 * 4);
    float* weT    = (float*)alloc(10752 * 4);
    float* msg    = (float*)alloc((size_t)EF * 64 * 4);

    // zero cnt + cnt2 (contiguous span)
    size_t zspan = (char*)cnt2 - (char*)cnt + (size_t)NN * 4;
    hipMemsetAsync(cnt, 0, zspan, stream);

    k_transpose<<<117, 256, 0, stream>>>(mw1, mw2, mw3, hw1, hw2, hw3, we,
                                         mw1T, mw2T, mw3T, hw1T, hw2T, hw3T, weT);
    k_count<<<(EF + 255) / 256, 256, 0, stream>>>(dst, mask, cnt);
    k_scan<<<1, 1024, 0, stream>>>(cnt, row_off);
    k_scatter<<<(EF + 255) / 256, 256, 0, stream>>>(dst, mask, row_off, cnt2, eidx);
    k_node<<<NN / 4, 256, 0, stream>>>(angle, mol, gen, cnt, wq, bq, wk, bk, wv, bv,
                                       wskip, bskip, weT, selff, qf, kf, vf, skipf, qwe);
    k_edge_mlp<<<EF / 64, 64, 0, stream>>>(x, angle, mol, src, dst,
                                           mw1T, mb1, mw2T, mb2, mw3T, mb3, msg);
    k_attn<<<NN / 4, 256, 0, stream>>>(row_off, eidx, src, msg, qf, kf, vf,
                                       qwe, selff, skipf, we, outb);
    k_final<<<(NN + 63) / 64, 64, 0, stream>>>(outb, hw1T, hb1, hw2T, hb2, hw3T, hb3, out);
}

// Round 2
// 489.481 us; speedup vs baseline: 2.5003x; 2.5003x over previous
//
#include <hip/hip_runtime.h>
#include <hip/hip_bf16.h>
#include <math.h>

#define NN 20000
#define EF 720000

typedef float  f4 __attribute__((ext_vector_type(4)));
typedef unsigned int u4 __attribute__((ext_vector_type(4)));

__device__ __forceinline__ void MFMA(f4& c, u4 a, u4 b) {
    // D = A*B + C, 16x16x32 bf16. a = A-frag (row=lane&15, k=(lane>>4)*8+j),
    // b = B-frag (col=lane&15, k=(lane>>4)*8+j), C/D: col=lane&15, row=(lane>>4)*4+reg.
    asm("v_mfma_f32_16x16x32_bf16 %0, %1, %2, %0" : "+v"(c) : "v"(a), "v"(b));
}

__device__ __forceinline__ unsigned pk(float a, float b) {
    __hip_bfloat162 t = __halves2bfloat162(__float2bfloat16(a), __float2bfloat16(b));
    unsigned u; __builtin_memcpy(&u, &t, 4); return u;
}
__device__ __forceinline__ float bf2f(unsigned short u) {
    return __builtin_bit_cast(float, (unsigned)u << 16);
}

// ---------------------------------------------------------------- prep: bf16 weights + transposes
__global__ __launch_bounds__(256) void k_prep(
    const float* __restrict__ mw1, const float* __restrict__ mb1,
    const float* __restrict__ mw2, const float* __restrict__ mw3,
    const float* __restrict__ hw1, const float* __restrict__ hw2, const float* __restrict__ hw3,
    const float* __restrict__ we,
    __hip_bfloat16* __restrict__ W1b, __hip_bfloat16* __restrict__ W2b, __hip_bfloat16* __restrict__ W3b,
    float* __restrict__ hw1T, float* __restrict__ hw2T, float* __restrict__ hw3T,
    float* __restrict__ weT)
{
    int t = blockIdx.x * 256 + threadIdx.x;
    if (t < 2048) {  // W1b[ch][k], K=32: k<21 weights, k==21 bias, rest 0
        int ch = t >> 5, k = t & 31;
        float v = (k < 21) ? mw1[k * 64 + ch] : (k == 21 ? mb1[ch] : 0.f);
        W1b[t] = __float2bfloat16(v); return;
    }
    t -= 2048;
    if (t < 4096) { int ch = t >> 6, k = t & 63; W2b[t] = __float2bfloat16(mw2[k * 64 + ch]); return; }
    t -= 4096;
    if (t < 4096) { int ch = t >> 6, k = t & 63; W3b[t] = __float2bfloat16(mw3[k * 64 + ch]); return; }
    t -= 4096;
    if (t < 4096) { int c = t >> 6, k = t & 63; hw1T[t] = hw1[k * 64 + c]; return; }
    t -= 4096;
    if (t < 4096) { int c = t >> 6, k = t & 63; hw2T[t] = hw2[k * 64 + c]; return; }
    t -= 4096;
    if (t < 1280) { int c = t >> 6, k = t & 63; hw3T[t] = hw3[k * 20 + c]; return; }
    t -= 1280;
    if (t < 10752) { int cf = t / 84, a = t % 84; weT[t] = we[a * 128 + cf]; return; }
}

// ---------------------------------------------------------------- CSR via binary search
// dst[0:Eact] is non-decreasing (np.nonzero row-major order); real edges are a mask prefix.
__global__ __launch_bounds__(256) void k_csr(
    const int* __restrict__ dst, const float* __restrict__ mask, int* __restrict__ row_off)
{
    int n = blockIdx.x * 256 + threadIdx.x;
    if (n > NN) return;
    int lo = 0, hi = EF;                       // Eact = first i with mask[i] < 0.5
    while (lo < hi) { int mid = (lo + hi) >> 1; if (mask[mid] > 0.5f) lo = mid + 1; else hi = mid; }
    int Ea = lo;
    lo = 0; hi = Ea;                           // row_off[n] = first i in [0,Ea) with dst[i] >= n
    while (lo < hi) { int mid = (lo + hi) >> 1; if (dst[mid] < n) lo = mid + 1; else hi = mid; }
    row_off[n] = lo;
}

// ---------------------------------------------------------------- node features + projections + qwe
__global__ __launch_bounds__(256) void k_node(
    const float* __restrict__ angle, const float* __restrict__ mol, const float* __restrict__ gen,
    const int* __restrict__ row_off,
    const float* __restrict__ wq, const float* __restrict__ bq,
    const float* __restrict__ wk, const float* __restrict__ bk,
    const float* __restrict__ wv, const float* __restrict__ bv,
    const float* __restrict__ wskip, const float* __restrict__ bskip,
    const float* __restrict__ weT,
    float* __restrict__ selff, float* __restrict__ qf, float* __restrict__ kf,
    float* __restrict__ vf, float* __restrict__ skipf, float* __restrict__ qwe)
{
    __shared__ float qlds[4 * 128];
    int wid = threadIdx.x >> 6, lane = threadIdx.x & 63;
    int n = blockIdx.x * 4 + wid;

    float an = angle[n];
    float sv, cv; sincosf(an, &sv, &cv);
    float degf = (float)(row_off[n + 1] - row_off[n]);
    float sf[20];
    sf[0] = sv; sf[1] = cv;
#pragma unroll
    for (int j = 0; j < 16; j++) sf[2 + j] = mol[n * 16 + j];
    sf[18] = gen[n];
    sf[19] = degf;

    float sval = (lane == 0) ? sv : (lane == 1) ? cv :
                 (lane < 18) ? mol[n * 16 + (lane - 2)] :
                 (lane == 18) ? gen[n] : degf;
    if (lane < 20) selff[n * 20 + lane] = sval;

    float q0 = bq[lane], q1 = bq[64 + lane];
    float k0 = bk[lane], k1 = bk[64 + lane];
    float v0 = bv[lane], v1 = bv[64 + lane];
    float sk = bskip[lane];
#pragma unroll
    for (int a = 0; a < 20; a++) {
        float s = sf[a];
        q0 += s * wq[a * 128 + lane];      q1 += s * wq[a * 128 + 64 + lane];
        k0 += s * wk[a * 128 + lane];      k1 += s * wk[a * 128 + 64 + lane];
        v0 += s * wv[a * 128 + lane];      v1 += s * wv[a * 128 + 64 + lane];
        sk += s * wskip[a * 64 + lane];
    }
    qf[n * 128 + lane] = q0; qf[n * 128 + 64 + lane] = q1;
    kf[n * 128 + lane] = k0; kf[n * 128 + 64 + lane] = k1;
    vf[n * 128 + lane] = v0; vf[n * 128 + 64 + lane] = v1;
    skipf[n * 64 + lane] = sk;
    qlds[wid * 128 + lane] = q0; qlds[wid * 128 + 64 + lane] = q1;
    __syncthreads();

#pragma unroll
    for (int r = 0; r < 3; r++) {
        int o = r * 64 + lane;
        if (o < 168) {
            int h = (o >= 84) ? 1 : 0;
            int a = o - 84 * h;
            float acc = 0.f, acc2 = 0.f;
#pragma unroll
            for (int c = 0; c < 64; c += 2) {
                acc  += qlds[wid * 128 + h * 64 + c]     * weT[(h * 64 + c) * 84 + a];
                acc2 += qlds[wid * 128 + h * 64 + c + 1] * weT[(h * 64 + c + 1) * 84 + a];
            }
            qwe[n * 168 + o] = acc + acc2;
        }
    }
}

// ---------------------------------------------------------------- edge MLP via MFMA (1 wave = 64 edges)
// LDS H layout: element (e,k) -> byte = e*128 + ((g ^ (e&7))<<4) + (k&7)*2, g = k>>3  (K=64)
//               stage-1 input (K=32): byte = e*64 + ((g ^ (e&3))<<4) + (k&7)*2, g = k>>3
__device__ __forceinline__ void write_tiles(char* lds, int l, f4 (&acc)[4][4], const float* bias)
{
#pragma unroll
    for (int m = 0; m < 4; m++) {
        f4 bv;
        if (bias) bv = *(const f4*)(bias + m * 16 + ((l >> 4) << 2));
        else      { bv.x = 0.f; bv.y = 0.f; bv.z = 0.f; bv.w = 0.f; }
#pragma unroll
        for (int n = 0; n < 4; n++) {
            f4 v = acc[m][n];
            float v0 = fmaxf(v.x + bv.x, 0.f);
            float v1 = fmaxf(v.y + bv.y, 0.f);
            float v2 = fmaxf(v.z + bv.z, 0.f);
            float v3 = fmaxf(v.w + bv.w, 0.f);
            int e   = n * 16 + (l & 15);
            int ch0 = m * 16 + ((l >> 4) << 2);
            int byte = e * 128 + ((((ch0 >> 3) ^ (e & 7))) << 4) + (ch0 & 7) * 2;
            uint2 w; w.x = pk(v0, v1); w.y = pk(v2, v3);
            *(uint2*)(lds + byte) = w;
        }
    }
}

__global__ __launch_bounds__(64) void k_edge_mfma(
    const float* __restrict__ x, const float* __restrict__ angle, const float* __restrict__ mol,
    const int* __restrict__ src, const int* __restrict__ dst,
    const __hip_bfloat16* __restrict__ W1b, const __hip_bfloat16* __restrict__ W2b,
    const __hip_bfloat16* __restrict__ W3b,
    const float* __restrict__ mb2, const float* __restrict__ mb3,
    __hip_bfloat16* __restrict__ msg)
{
    __shared__ char lds[64 * 128];
    int l = threadIdx.x;
    int e0 = blockIdx.x * 64;

    // ---- per-edge relative features (f32), pack to bf16, stage to LDS (K=32 layout)
    int s = src[e0 + l], d = dst[e0 + l];
    float2 xs = ((const float2*)x)[s], xd = ((const float2*)x)[d];
    float dx = xs.x - xd.x, dy = xs.y - xd.y;
    float r = sqrtf(fmaxf(dx * dx + dy * dy, 1e-12f));
    float da = angle[s] - angle[d];
    float sv, cv; sincosf(da, &sv, &cv);
    const float4* m4 = (const float4*)mol;
    float4 sa = m4[s * 4 + 0], sb = m4[s * 4 + 1], sc = m4[s * 4 + 2], sd = m4[s * 4 + 3];
    float4 ta = m4[d * 4 + 0], tb = m4[d * 4 + 1], tc = m4[d * 4 + 2], td = m4[d * 4 + 3];
    float f[22];
    f[0] = dx; f[1] = dy; f[2] = r; f[3] = sv; f[4] = cv;
    f[5]  = sa.x - ta.x; f[6]  = sa.y - ta.y; f[7]  = sa.z - ta.z; f[8]  = sa.w - ta.w;
    f[9]  = sb.x - tb.x; f[10] = sb.y - tb.y; f[11] = sb.z - tb.z; f[12] = sb.w - tb.w;
    f[13] = sc.x - tc.x; f[14] = sc.y - tc.y; f[15] = sc.z - tc.z; f[16] = sc.w - tc.w;
    f[17] = sd.x - td.x; f[18] = sd.y - td.y; f[19] = sd.z - td.z; f[20] = sd.w - td.w;
    f[21] = 1.f;  // bias row
    unsigned p[16];
#pragma unroll
    for (int j = 0; j < 11; j++) p[j] = pk(f[2 * j], f[2 * j + 1]);
#pragma unroll
    for (int j = 11; j < 16; j++) p[j] = 0u;
#pragma unroll
    for (int g = 0; g < 4; g++) {
        int byte = l * 64 + ((g ^ (l & 3)) << 4);
        u4 w; w.x = p[4 * g]; w.y = p[4 * g + 1]; w.z = p[4 * g + 2]; w.w = p[4 * g + 3];
        *(u4*)(lds + byte) = w;
    }
    __syncthreads();

    // ---- stage 1: 32 -> 64
    u4 B1[4];
#pragma unroll
    for (int n = 0; n < 4; n++) {
        int e = n * 16 + (l & 15);
        int byte = e * 64 + ((((l >> 4) & 3) ^ (e & 3)) << 4);
        B1[n] = *(const u4*)(lds + byte);
    }
    __syncthreads();

    f4 acc[4][4];
#pragma unroll
    for (int m = 0; m < 4; m++)
#pragma unroll
        for (int n = 0; n < 4; n++) { acc[m][n].x = 0.f; acc[m][n].y = 0.f; acc[m][n].z = 0.f; acc[m][n].w = 0.f; }

    const unsigned short* W1u = (const unsigned short*)W1b;
    const unsigned short* W2u = (const unsigned short*)W2b;
    const unsigned short* W3u = (const unsigned short*)W3b;
#pragma unroll
    for (int m = 0; m < 4; m++) {
        u4 w = *(const u4*)(W1u + (m * 16 + (l & 15)) * 32 + (l >> 4) * 8);
#pragma unroll
        for (int n = 0; n < 4; n++) MFMA(acc[m][n], w, B1[n]);
    }
    write_tiles(lds, l, acc, nullptr);  // bias folded into K-row 21
    __syncthreads();

    // ---- stage 2: 64 -> 64
    u4 B2[4][2];
#pragma unroll
    for (int n = 0; n < 4; n++)
#pragma unroll
        for (int ks = 0; ks < 2; ks++) {
            int e = n * 16 + (l & 15);
            int g = ks * 4 + (l >> 4);
            B2[n][ks] = *(const u4*)(lds + e * 128 + ((g ^ (e & 7)) << 4));
        }
    __syncthreads();
#pragma unroll
    for (int m = 0; m < 4; m++)
#pragma unroll
        for (int n = 0; n < 4; n++) { acc[m][n].x = 0.f; acc[m][n].y = 0.f; acc[m][n].z = 0.f; acc[m][n].w = 0.f; }
#pragma unroll
    for (int m = 0; m < 4; m++)
#pragma unroll
        for (int ks = 0; ks < 2; ks++) {
            u4 w = *(const u4*)(W2u + (m * 16 + (l & 15)) * 64 + ks * 32 + (l >> 4) * 8);
#pragma unroll
            for (int n = 0; n < 4; n++) MFMA(acc[m][n], w, B2[n][ks]);
        }
    write_tiles(lds, l, acc, mb2);
    __syncthreads();

    // ---- stage 3: 64 -> 64
#pragma unroll
    for (int n = 0; n < 4; n++)
#pragma unroll
        for (int ks = 0; ks < 2; ks++) {
            int e = n * 16 + (l & 15);
            int g = ks * 4 + (l >> 4);
            B2[n][ks] = *(const u4*)(lds + e * 128 + ((g ^ (e & 7)) << 4));
        }
    __syncthreads();
#pragma unroll
    for (int m = 0; m < 4; m++)
#pragma unroll
        for (int n = 0; n < 4; n++) { acc[m][n].x = 0.f; acc[m][n].y = 0.f; acc[m][n].z = 0.f; acc[m][n].w = 0.f; }
#pragma unroll
    for (int m = 0; m < 4; m++)
#pragma unroll
        for (int ks = 0; ks < 2; ks++) {
            u4 w = *(const u4*)(W3u + (m * 16 + (l & 15)) * 64 + ks * 32 + (l >> 4) * 8);
#pragma unroll
            for (int n = 0; n < 4; n++) MFMA(acc[m][n], w, B2[n][ks]);
        }
    write_tiles(lds, l, acc, mb3);
    __syncthreads();

    // ---- coalesced readout: msg[e][c] bf16, 8 edges / iter
#pragma unroll
    for (int it = 0; it < 8; it++) {
        int e = it * 8 + (l >> 3);
        int g = l & 7;
        u4 vv = *(const u4*)(lds + e * 128 + ((g ^ (e & 7)) << 4));
        *(u4*)((unsigned short*)msg + (size_t)(e0 + e) * 64 + g * 8) = vv;
    }
}

// ---------------------------------------------------------------- attention aggregate (wave per node)
__global__ __launch_bounds__(256) void k_attn(
    const int* __restrict__ row_off, const int* __restrict__ src,
    const __hip_bfloat16* __restrict__ msg,
    const float* __restrict__ qf, const float* __restrict__ kf, const float* __restrict__ vf,
    const float* __restrict__ qwe, const float* __restrict__ selff, const float* __restrict__ skipf,
    const float* __restrict__ we,
    float* __restrict__ outb)
{
    __shared__ float we_lds[84 * 128];
    __shared__ float wm[4 * 128];
    int tid = threadIdx.x, wid = tid >> 6, lane = tid & 63;
    for (int i = tid; i < 84 * 128; i += 256) we_lds[i] = we[i];
    __syncthreads();

    int n = blockIdx.x * 4 + wid;
    float q0 = qf[n * 128 + lane], q1 = qf[n * 128 + 64 + lane];
    float qm0 = qwe[n * 168 + lane], qm1 = qwe[n * 168 + 84 + lane];
    float sf[20];
#pragma unroll
    for (int j = 0; j < 20; j++) sf[j] = selff[n * 20 + j];
    float a00 = 0.f, a01 = 0.f;
#pragma unroll
    for (int j = 0; j < 20; j++) {
        a00 += sf[j] * qwe[n * 168 + 64 + j];
        a01 += sf[j] * qwe[n * 168 + 84 + 64 + j];
    }

    const unsigned short* msgu = (const unsigned short*)msg;
    int r0 = row_off[n], r1 = row_off[n + 1];
    float S0 = 0.f, S1 = 0.f, Wv0 = 0.f, Wv1 = 0.f, Wm0 = 0.f, Wm1 = 0.f;
#pragma unroll 2
    for (int e = r0; e < r1; e++) {
        int s = src[e];
        float mc = bf2f(msgu[(size_t)e * 64 + lane]);
        float k0 = kf[s * 128 + lane], k1 = kf[s * 128 + 64 + lane];
        float v0 = vf[s * 128 + lane], v1 = vf[s * 128 + 64 + lane];
        float t0 = q0 * k0 + mc * qm0;
        float t1 = q1 * k1 + mc * qm1;
#pragma unroll
        for (int mk = 1; mk < 64; mk <<= 1) {
            t0 += __shfl_xor(t0, mk, 64);
            t1 += __shfl_xor(t1, mk, 64);
        }
        float w0 = __expf((t0 + a00) * 0.125f);
        float w1 = __expf((t1 + a01) * 0.125f);
        S0 += w0; S1 += w1;
        Wv0 += w0 * v0; Wv1 += w1 * v1;
        Wm0 += w0 * mc; Wm1 += w1 * mc;
    }
    wm[wid * 128 + lane] = Wm0;
    wm[wid * 128 + 64 + lane] = Wm1;
    __syncthreads();

    float acc0 = 0.f, acc1 = 0.f;
    for (int a = 0; a < 64; a += 2) {
        float wma0 = wm[wid * 128 + a],     wmb0 = wm[wid * 128 + 64 + a];
        float wma1 = wm[wid * 128 + a + 1], wmb1 = wm[wid * 128 + 64 + a + 1];
        acc0 += wma0 * we_lds[a * 128 + lane]      + wma1 * we_lds[(a + 1) * 128 + lane];
        acc1 += wmb0 * we_lds[a * 128 + 64 + lane] + wmb1 * we_lds[(a + 1) * 128 + 64 + lane];
    }
#pragma unroll
    for (int j = 0; j < 20; j++) {
        acc0 += S0 * sf[j] * we_lds[(64 + j) * 128 + lane];
        acc1 += S1 * sf[j] * we_lds[(64 + j) * 128 + 64 + lane];
    }
    float o0 = (Wv0 + acc0) / (S0 + 1e-16f);
    float o1 = (Wv1 + acc1) / (S1 + 1e-16f);
    outb[n * 64 + lane] = 0.5f * (o0 + o1) + skipf[n * 64 + lane];
}

// ---------------------------------------------------------------- final MLP + split outputs
__global__ __launch_bounds__(64) void k_final(
    const float* __restrict__ outb,
    const float* __restrict__ hw1T, const float* __restrict__ hb1,
    const float* __restrict__ hw2T, const float* __restrict__ hb2,
    const float* __restrict__ hw3T, const float* __restrict__ hb3,
    float* __restrict__ out)
{
    __shared__ float ul[64 * 65];
    int lane = threadIdx.x;
    int n = blockIdx.x * 64 + lane;
    bool ok = (n < NN);
    int nn = ok ? n : (NN - 1);

    float h[64];
#pragma unroll
    for (int k = 0; k < 64; k++) h[k] = outb[nn * 64 + k];

    for (int c = 0; c < 64; c++) {
        float a0 = hb1[c], a1 = 0.f, a2 = 0.f, a3 = 0.f;
#pragma unroll
        for (int k = 0; k < 64; k += 4) {
            a0 += h[k]     * hw1T[c * 64 + k];
            a1 += h[k + 1] * hw1T[c * 64 + k + 1];
            a2 += h[k + 2] * hw1T[c * 64 + k + 2];
            a3 += h[k + 3] * hw1T[c * 64 + k + 3];
        }
        ul[c * 65 + lane] = fmaxf((a0 + a1) + (a2 + a3), 0.f);
    }
#pragma unroll
    for (int k = 0; k < 64; k++) h[k] = ul[k * 65 + lane];

    for (int c = 0; c < 64; c++) {
        float a0 = hb2[c], a1 = 0.f, a2 = 0.f, a3 = 0.f;
#pragma unroll
        for (int k = 0; k < 64; k += 4) {
            a0 += h[k]     * hw2T[c * 64 + k];
            a1 += h[k + 1] * hw2T[c * 64 + k + 1];
            a2 += h[k + 2] * hw2T[c * 64 + k + 2];
            a3 += h[k + 3] * hw2T[c * 64 + k + 3];
        }
        ul[c * 65 + lane] = fmaxf((a0 + a1) + (a2 + a3), 0.f);
    }
#pragma unroll
    for (int k = 0; k < 64; k++) h[k] = ul[k * 65 + lane];

    for (int c = 0; c < 20; c++) {
        float a0 = hb3[c], a1 = 0.f, a2 = 0.f, a3 = 0.f;
#pragma unroll
        for (int k = 0; k < 64; k += 4) {
            a0 += h[k]     * hw3T[c * 64 + k];
            a1 += h[k + 1] * hw3T[c * 64 + k + 1];
            a2 += h[k + 2] * hw3T[c * 64 + k + 2];
            a3 += h[k + 3] * hw3T[c * 64 + k + 3];
        }
        float upd = (a0 + a1) + (a2 + a3);
        if (ok) {
            if (c < 2)       out[n * 2 + c] = upd;
            else if (c == 2) out[2 * NN + n] = upd;
            else if (c < 19) out[3 * NN + n * 16 + (c - 3)] = upd;
            else             out[19 * NN + n] = upd;
        }
    }
}

// ---------------------------------------------------------------- launch
extern "C" void kernel_launch(void* const* d_in, const int* in_sizes, int n_in,
                              void* d_out, int out_size, void* d_ws, size_t ws_size,
                              hipStream_t stream)
{
    const float* x      = (const float*)d_in[0];
    const float* angle  = (const float*)d_in[1];
    const float* mol    = (const float*)d_in[2];
    const float* gen    = (const float*)d_in[3];
    const int*   src    = (const int*)d_in[4];
    const int*   dst    = (const int*)d_in[5];
    const float* mask   = (const float*)d_in[6];
    const float* mw1    = (const float*)d_in[7];
    const float* mb1    = (const float*)d_in[8];
    const float* mw2    = (const float*)d_in[9];
    const float* mb2    = (const float*)d_in[10];
    const float* mw3    = (const float*)d_in[11];
    const float* mb3    = (const float*)d_in[12];
    const float* wq     = (const float*)d_in[13];
    const float* bq     = (const float*)d_in[14];
    const float* wk     = (const float*)d_in[15];
    const float* bk     = (const float*)d_in[16];
    const float* wv     = (const float*)d_in[17];
    const float* bv     = (const float*)d_in[18];
    const float* we     = (const float*)d_in[19];
    const float* wskip  = (const float*)d_in[20];
    const float* bskip  = (const float*)d_in[21];
    const float* hw1    = (const float*)d_in[22];
    const float* hb1    = (const float*)d_in[23];
    const float* hw2    = (const float*)d_in[24];
    const float* hb2    = (const float*)d_in[25];
    const float* hw3    = (const float*)d_in[26];
    const float* hb3    = (const float*)d_in[27];
    float* out = (float*)d_out;

    char* p = (char*)d_ws;
    auto alloc = [&](size_t bytes) -> void* {
        void* r = (void*)p;
        p += (bytes + 255) & ~(size_t)255;
        return r;
    };
    int*   row_off = (int*)alloc((NN + 1) * 4);
    float* selff   = (float*)alloc((size_t)NN * 20 * 4);
    float* qf      = (float*)alloc((size_t)NN * 128 * 4);
    float* kf      = (float*)alloc((size_t)NN * 128 * 4);
    float* vf      = (float*)alloc((size_t)NN * 128 * 4);
    float* skipf   = (float*)alloc((size_t)NN * 64 * 4);
    float* qwe     = (float*)alloc((size_t)NN * 168 * 4);
    float* outb    = (float*)alloc((size_t)NN * 64 * 4);
    __hip_bfloat16* W1b = (__hip_bfloat16*)alloc(2048 * 2);
    __hip_bfloat16* W2b = (__hip_bfloat16*)alloc(4096 * 2);
    __hip_bfloat16* W3b = (__hip_bfloat16*)alloc(4096 * 2);
    float* hw1T    = (float*)alloc(4096 * 4);
    float* hw2T    = (float*)alloc(4096 * 4);
    float* hw3T    = (float*)alloc(1280 * 4);
    float* weT     = (float*)alloc(10752 * 4);
    __hip_bfloat16* msg = (__hip_bfloat16*)alloc((size_t)EF * 64 * 2);

    k_prep<<<119, 256, 0, stream>>>(mw1, mb1, mw2, mw3, hw1, hw2, hw3, we,
                                    W1b, W2b, W3b, hw1T, hw2T, hw3T, weT);
    k_csr<<<(NN + 256) / 256, 256, 0, stream>>>(dst, mask, row_off);
    k_node<<<NN / 4, 256, 0, stream>>>(angle, mol, gen, row_off, wq, bq, wk, bk, wv, bv,
                                       wskip, bskip, weT, selff, qf, kf, vf, skipf, qwe);
    k_edge_mfma<<<EF / 64, 64, 0, stream>>>(x, angle, mol, src, dst,
                                            W1b, W2b, W3b, mb2, mb3, msg);
    k_attn<<<NN / 4, 256, 0, stream>>>(row_off, src, msg, qf, kf, vf,
                                       qwe, selff, skipf, we, outb);
    k_final<<<(NN + 63) / 64, 64, 0, stream>>>(outb, hw1T, hb1, hw2T, hb2, hw3T, hb3, out);
}

// Round 3
// 346.633 us; speedup vs baseline: 3.5306x; 1.4121x over previous
//
#include <hip/hip_runtime.h>
#include <hip/hip_bf16.h>
#include <math.h>

#define NN 20000
#define EF 720000

typedef float  f4 __attribute__((ext_vector_type(4)));
typedef unsigned int u4 __attribute__((ext_vector_type(4)));

__device__ __forceinline__ void MFMA(f4& c, u4 a, u4 b) {
    asm("v_mfma_f32_16x16x32_bf16 %0, %1, %2, %0" : "+v"(c) : "v"(a), "v"(b));
}

__device__ __forceinline__ unsigned pk(float a, float b) {
    __hip_bfloat162 t = __halves2bfloat162(__float2bfloat16(a), __float2bfloat16(b));
    unsigned u; __builtin_memcpy(&u, &t, 4); return u;
}
__device__ __forceinline__ float bf2f(unsigned short u) {
    return __builtin_bit_cast(float, (unsigned)u << 16);
}
__device__ __forceinline__ float dot4(f4 a, f4 b) {
    return a.x * b.x + a.y * b.y + a.z * b.z + a.w * b.w;
}
__device__ __forceinline__ void fma4(f4& acc, float w, f4 v) {
    acc.x += w * v.x; acc.y += w * v.y; acc.z += w * v.z; acc.w += w * v.w;
}

// ---------------------------------------------------------------- prep: bf16 weights + transposes
__global__ __launch_bounds__(256) void k_prep(
    const float* __restrict__ mw1, const float* __restrict__ mb1,
    const float* __restrict__ mw2, const float* __restrict__ mw3,
    const float* __restrict__ hw1, const float* __restrict__ hw2, const float* __restrict__ hw3,
    const float* __restrict__ we,
    __hip_bfloat16* __restrict__ W1b, __hip_bfloat16* __restrict__ W2b, __hip_bfloat16* __restrict__ W3b,
    float* __restrict__ hw1T, float* __restrict__ hw2T, float* __restrict__ hw3T,
    float* __restrict__ weT)
{
    int t = blockIdx.x * 256 + threadIdx.x;
    if (t < 2048) {  // W1b[ch][k], K=32: k<21 weights, k==21 bias, rest 0
        int ch = t >> 5, k = t & 31;
        float v = (k < 21) ? mw1[k * 64 + ch] : (k == 21 ? mb1[ch] : 0.f);
        W1b[t] = __float2bfloat16(v); return;
    }
    t -= 2048;
    if (t < 4096) { int ch = t >> 6, k = t & 63; W2b[t] = __float2bfloat16(mw2[k * 64 + ch]); return; }
    t -= 4096;
    if (t < 4096) { int ch = t >> 6, k = t & 63; W3b[t] = __float2bfloat16(mw3[k * 64 + ch]); return; }
    t -= 4096;
    if (t < 4096) { int c = t >> 6, k = t & 63; hw1T[t] = hw1[k * 64 + c]; return; }
    t -= 4096;
    if (t < 4096) { int c = t >> 6, k = t & 63; hw2T[t] = hw2[k * 64 + c]; return; }
    t -= 4096;
    if (t < 1280) { int c = t >> 6, k = t & 63; hw3T[t] = hw3[k * 20 + c]; return; }
    t -= 1280;
    if (t < 10752) { int cf = t / 84, a = t % 84; weT[t] = we[a * 128 + cf]; return; }
}

// ---------------------------------------------------------------- CSR via binary search
__global__ __launch_bounds__(256) void k_csr(
    const int* __restrict__ dst, const float* __restrict__ mask, int* __restrict__ row_off)
{
    int n = blockIdx.x * 256 + threadIdx.x;
    if (n > NN) return;
    int lo = 0, hi = EF;
    while (lo < hi) { int mid = (lo + hi) >> 1; if (mask[mid] > 0.5f) lo = mid + 1; else hi = mid; }
    int Ea = lo;
    lo = 0; hi = Ea;
    while (lo < hi) { int mid = (lo + hi) >> 1; if (dst[mid] < n) lo = mid + 1; else hi = mid; }
    row_off[n] = lo;
}

// ---------------------------------------------------------------- node features + projections + qwe
__global__ __launch_bounds__(256) void k_node(
    const float* __restrict__ angle, const float* __restrict__ mol, const float* __restrict__ gen,
    const int* __restrict__ row_off,
    const float* __restrict__ wq, const float* __restrict__ bq,
    const float* __restrict__ wk, const float* __restrict__ bk,
    const float* __restrict__ wv, const float* __restrict__ bv,
    const float* __restrict__ wskip, const float* __restrict__ bskip,
    const float* __restrict__ weT,
    float* __restrict__ selff, float* __restrict__ qf, float* __restrict__ kf,
    float* __restrict__ vf, float* __restrict__ skipf, float* __restrict__ qwe)
{
    __shared__ float qlds[4 * 128];
    int wid = threadIdx.x >> 6, lane = threadIdx.x & 63;
    int n = blockIdx.x * 4 + wid;

    float an = angle[n];
    float sv, cv; sincosf(an, &sv, &cv);
    float degf = (float)(row_off[n + 1] - row_off[n]);
    float sf[20];
    sf[0] = sv; sf[1] = cv;
#pragma unroll
    for (int j = 0; j < 16; j++) sf[2 + j] = mol[n * 16 + j];
    sf[18] = gen[n];
    sf[19] = degf;

    float sval = (lane == 0) ? sv : (lane == 1) ? cv :
                 (lane < 18) ? mol[n * 16 + (lane - 2)] :
                 (lane == 18) ? gen[n] : degf;
    if (lane < 20) selff[n * 20 + lane] = sval;

    float q0 = bq[lane], q1 = bq[64 + lane];
    float k0 = bk[lane], k1 = bk[64 + lane];
    float v0 = bv[lane], v1 = bv[64 + lane];
    float sk = bskip[lane];
#pragma unroll
    for (int a = 0; a < 20; a++) {
        float s = sf[a];
        q0 += s * wq[a * 128 + lane];      q1 += s * wq[a * 128 + 64 + lane];
        k0 += s * wk[a * 128 + lane];      k1 += s * wk[a * 128 + 64 + lane];
        v0 += s * wv[a * 128 + lane];      v1 += s * wv[a * 128 + 64 + lane];
        sk += s * wskip[a * 64 + lane];
    }
    qf[n * 128 + lane] = q0; qf[n * 128 + 64 + lane] = q1;
    kf[n * 128 + lane] = k0; kf[n * 128 + 64 + lane] = k1;
    vf[n * 128 + lane] = v0; vf[n * 128 + 64 + lane] = v1;
    skipf[n * 64 + lane] = sk;
    qlds[wid * 128 + lane] = q0; qlds[wid * 128 + 64 + lane] = q1;
    __syncthreads();

#pragma unroll
    for (int r = 0; r < 3; r++) {
        int o = r * 64 + lane;
        if (o < 168) {
            int h = (o >= 84) ? 1 : 0;
            int a = o - 84 * h;
            float acc = 0.f, acc2 = 0.f;
#pragma unroll
            for (int c = 0; c < 64; c += 2) {
                acc  += qlds[wid * 128 + h * 64 + c]     * weT[(h * 64 + c) * 84 + a];
                acc2 += qlds[wid * 128 + h * 64 + c + 1] * weT[(h * 64 + c + 1) * 84 + a];
            }
            qwe[n * 168 + o] = acc + acc2;
        }
    }
}

// ---------------------------------------------------------------- edge MLP via MFMA (1 wave = 64 edges)
__device__ __forceinline__ void write_tiles(char* lds, int l, f4 (&acc)[4][4], const float* bias)
{
#pragma unroll
    for (int m = 0; m < 4; m++) {
        f4 bv;
        if (bias) bv = *(const f4*)(bias + m * 16 + ((l >> 4) << 2));
        else      { bv.x = 0.f; bv.y = 0.f; bv.z = 0.f; bv.w = 0.f; }
#pragma unroll
        for (int n = 0; n < 4; n++) {
            f4 v = acc[m][n];
            float v0 = fmaxf(v.x + bv.x, 0.f);
            float v1 = fmaxf(v.y + bv.y, 0.f);
            float v2 = fmaxf(v.z + bv.z, 0.f);
            float v3 = fmaxf(v.w + bv.w, 0.f);
            int e   = n * 16 + (l & 15);
            int ch0 = m * 16 + ((l >> 4) << 2);
            int byte = e * 128 + ((((ch0 >> 3) ^ (e & 7))) << 4) + (ch0 & 7) * 2;
            uint2 w; w.x = pk(v0, v1); w.y = pk(v2, v3);
            *(uint2*)(lds + byte) = w;
        }
    }
}

__global__ __launch_bounds__(64) void k_edge_mfma(
    const float* __restrict__ x, const float* __restrict__ angle, const float* __restrict__ mol,
    const int* __restrict__ src, const int* __restrict__ dst,
    const __hip_bfloat16* __restrict__ W1b, const __hip_bfloat16* __restrict__ W2b,
    const __hip_bfloat16* __restrict__ W3b,
    const float* __restrict__ mb2, const float* __restrict__ mb3,
    __hip_bfloat16* __restrict__ msg)
{
    __shared__ char lds[64 * 128];
    int l = threadIdx.x;
    int e0 = blockIdx.x * 64;

    int s = src[e0 + l], d = dst[e0 + l];
    float2 xs = ((const float2*)x)[s], xd = ((const float2*)x)[d];
    float dx = xs.x - xd.x, dy = xs.y - xd.y;
    float r = sqrtf(fmaxf(dx * dx + dy * dy, 1e-12f));
    float da = angle[s] - angle[d];
    float sv, cv; sincosf(da, &sv, &cv);
    const float4* m4 = (const float4*)mol;
    float4 sa = m4[s * 4 + 0], sb = m4[s * 4 + 1], sc = m4[s * 4 + 2], sd = m4[s * 4 + 3];
    float4 ta = m4[d * 4 + 0], tb = m4[d * 4 + 1], tc = m4[d * 4 + 2], td = m4[d * 4 + 3];
    float f[22];
    f[0] = dx; f[1] = dy; f[2] = r; f[3] = sv; f[4] = cv;
    f[5]  = sa.x - ta.x; f[6]  = sa.y - ta.y; f[7]  = sa.z - ta.z; f[8]  = sa.w - ta.w;
    f[9]  = sb.x - tb.x; f[10] = sb.y - tb.y; f[11] = sb.z - tb.z; f[12] = sb.w - tb.w;
    f[13] = sc.x - tc.x; f[14] = sc.y - tc.y; f[15] = sc.z - tc.z; f[16] = sc.w - tc.w;
    f[17] = sd.x - td.x; f[18] = sd.y - td.y; f[19] = sd.z - td.z; f[20] = sd.w - td.w;
    f[21] = 1.f;
    unsigned p[16];
#pragma unroll
    for (int j = 0; j < 11; j++) p[j] = pk(f[2 * j], f[2 * j + 1]);
#pragma unroll
    for (int j = 11; j < 16; j++) p[j] = 0u;
#pragma unroll
    for (int g = 0; g < 4; g++) {
        int byte = l * 64 + ((g ^ (l & 3)) << 4);
        u4 w; w.x = p[4 * g]; w.y = p[4 * g + 1]; w.z = p[4 * g + 2]; w.w = p[4 * g + 3];
        *(u4*)(lds + byte) = w;
    }
    __syncthreads();

    u4 B1[4];
#pragma unroll
    for (int n = 0; n < 4; n++) {
        int e = n * 16 + (l & 15);
        int byte = e * 64 + ((((l >> 4) & 3) ^ (e & 3)) << 4);
        B1[n] = *(const u4*)(lds + byte);
    }
    __syncthreads();

    f4 acc[4][4];
#pragma unroll
    for (int m = 0; m < 4; m++)
#pragma unroll
        for (int n = 0; n < 4; n++) { acc[m][n].x = 0.f; acc[m][n].y = 0.f; acc[m][n].z = 0.f; acc[m][n].w = 0.f; }

    const unsigned short* W1u = (const unsigned short*)W1b;
    const unsigned short* W2u = (const unsigned short*)W2b;
    const unsigned short* W3u = (const unsigned short*)W3b;
#pragma unroll
    for (int m = 0; m < 4; m++) {
        u4 w = *(const u4*)(W1u + (m * 16 + (l & 15)) * 32 + (l >> 4) * 8);
#pragma unroll
        for (int n = 0; n < 4; n++) MFMA(acc[m][n], w, B1[n]);
    }
    write_tiles(lds, l, acc, nullptr);
    __syncthreads();

    u4 B2[4][2];
#pragma unroll
    for (int n = 0; n < 4; n++)
#pragma unroll
        for (int ks = 0; ks < 2; ks++) {
            int e = n * 16 + (l & 15);
            int g = ks * 4 + (l >> 4);
            B2[n][ks] = *(const u4*)(lds + e * 128 + ((g ^ (e & 7)) << 4));
        }
    __syncthreads();
#pragma unroll
    for (int m = 0; m < 4; m++)
#pragma unroll
        for (int n = 0; n < 4; n++) { acc[m][n].x = 0.f; acc[m][n].y = 0.f; acc[m][n].z = 0.f; acc[m][n].w = 0.f; }
#pragma unroll
    for (int m = 0; m < 4; m++)
#pragma unroll
        for (int ks = 0; ks < 2; ks++) {
            u4 w = *(const u4*)(W2u + (m * 16 + (l & 15)) * 64 + ks * 32 + (l >> 4) * 8);
#pragma unroll
            for (int n = 0; n < 4; n++) MFMA(acc[m][n], w, B2[n][ks]);
        }
    write_tiles(lds, l, acc, mb2);
    __syncthreads();

#pragma unroll
    for (int n = 0; n < 4; n++)
#pragma unroll
        for (int ks = 0; ks < 2; ks++) {
            int e = n * 16 + (l & 15);
            int g = ks * 4 + (l >> 4);
            B2[n][ks] = *(const u4*)(lds + e * 128 + ((g ^ (e & 7)) << 4));
        }
    __syncthreads();
#pragma unroll
    for (int m = 0; m < 4; m++)
#pragma unroll
        for (int n = 0; n < 4; n++) { acc[m][n].x = 0.f; acc[m][n].y = 0.f; acc[m][n].z = 0.f; acc[m][n].w = 0.f; }
#pragma unroll
    for (int m = 0; m < 4; m++)
#pragma unroll
        for (int ks = 0; ks < 2; ks++) {
            u4 w = *(const u4*)(W3u + (m * 16 + (l & 15)) * 64 + ks * 32 + (l >> 4) * 8);
#pragma unroll
            for (int n = 0; n < 4; n++) MFMA(acc[m][n], w, B2[n][ks]);
        }
    write_tiles(lds, l, acc, mb3);
    __syncthreads();

#pragma unroll
    for (int it = 0; it < 8; it++) {
        int e = it * 8 + (l >> 3);
        int g = l & 7;
        u4 vv = *(const u4*)(lds + e * 128 + ((g ^ (e & 7)) << 4));
        *(u4*)((unsigned short*)msg + (size_t)(e0 + e) * 64 + g * 8) = vv;
    }
}

// ---------------------------------------------------------------- attention aggregate
// wave = node; 4 edge-groups of 16 lanes; lane handles 4 channels per head.
__global__ __launch_bounds__(256) void k_attn(
    const int* __restrict__ row_off, const int* __restrict__ src,
    const __hip_bfloat16* __restrict__ msg,
    const float* __restrict__ qf, const float* __restrict__ kf, const float* __restrict__ vf,
    const float* __restrict__ qwe, const float* __restrict__ selff, const float* __restrict__ skipf,
    const float* __restrict__ we,
    float* __restrict__ outb)
{
    __shared__ float red[4][4][64];  // [wave][{WvA,WvB,WmA,WmB}][ch]
    int tid = threadIdx.x, wid = tid >> 6, lane = tid & 63;
    int g = lane >> 4, c16 = lane & 15;
    int n = blockIdx.x * 4 + wid;

    const f4* q4 = (const f4*)(qf + n * 128);
    f4 q0 = q4[c16], q1 = q4[16 + c16];
    f4 qm0 = *(const f4*)(qwe + n * 168 + 4 * c16);
    f4 qm1 = *(const f4*)(qwe + n * 168 + 84 + 4 * c16);

    float a00 = 0.f, a01 = 0.f;
#pragma unroll
    for (int j = 0; j < 20; j++) {
        float sfj = selff[n * 20 + j];
        a00 += sfj * qwe[n * 168 + 64 + j];
        a01 += sfj * qwe[n * 168 + 84 + 64 + j];
    }

    const unsigned short* msgu = (const unsigned short*)msg;
    int r0 = row_off[n], r1 = row_off[n + 1];
    int nit = (r1 - r0 + 3) >> 2;

    f4 Wv0 = {0,0,0,0}, Wv1 = {0,0,0,0}, Wm0 = {0,0,0,0}, Wm1 = {0,0,0,0};
    float S0 = 0.f, S1 = 0.f;

#pragma unroll 2
    for (int it = 0; it < nit; it++) {
        int e = r0 + it * 4 + g;
        bool ok = (e < r1);
        int ec = ok ? e : r0;
        int s = src[ec];
        const f4* kp = (const f4*)(kf + s * 128);
        const f4* vp = (const f4*)(vf + s * 128);
        f4 k0 = kp[c16], k1 = kp[16 + c16];
        f4 v0 = vp[c16], v1 = vp[16 + c16];
        ushort4 mu = *(const ushort4*)(msgu + (size_t)ec * 64 + 4 * c16);
        f4 mc; mc.x = bf2f(mu.x); mc.y = bf2f(mu.y); mc.z = bf2f(mu.z); mc.w = bf2f(mu.w);

        float t0 = dot4(q0, k0) + dot4(qm0, mc);
        float t1 = dot4(q1, k1) + dot4(qm1, mc);
#pragma unroll
        for (int mk = 1; mk < 16; mk <<= 1) {
            t0 += __shfl_xor(t0, mk, 64);
            t1 += __shfl_xor(t1, mk, 64);
        }
        float w0 = ok ? __expf((t0 + a00) * 0.125f) : 0.f;
        float w1 = ok ? __expf((t1 + a01) * 0.125f) : 0.f;
        S0 += w0; S1 += w1;
        fma4(Wv0, w0, v0); fma4(Wv1, w1, v1);
        fma4(Wm0, w0, mc); fma4(Wm1, w1, mc);
    }

    // cross-group reduction (all lanes end with full-node values)
#pragma unroll
    for (int mk = 16; mk <= 32; mk <<= 1) {
        Wv0.x += __shfl_xor(Wv0.x, mk, 64); Wv0.y += __shfl_xor(Wv0.y, mk, 64);
        Wv0.z += __shfl_xor(Wv0.z, mk, 64); Wv0.w += __shfl_xor(Wv0.w, mk, 64);
        Wv1.x += __shfl_xor(Wv1.x, mk, 64); Wv1.y += __shfl_xor(Wv1.y, mk, 64);
        Wv1.z += __shfl_xor(Wv1.z, mk, 64); Wv1.w += __shfl_xor(Wv1.w, mk, 64);
        Wm0.x += __shfl_xor(Wm0.x, mk, 64); Wm0.y += __shfl_xor(Wm0.y, mk, 64);
        Wm0.z += __shfl_xor(Wm0.z, mk, 64); Wm0.w += __shfl_xor(Wm0.w, mk, 64);
        Wm1.x += __shfl_xor(Wm1.x, mk, 64); Wm1.y += __shfl_xor(Wm1.y, mk, 64);
        Wm1.z += __shfl_xor(Wm1.z, mk, 64); Wm1.w += __shfl_xor(Wm1.w, mk, 64);
        S0 += __shfl_xor(S0, mk, 64); S1 += __shfl_xor(S1, mk, 64);
    }

    if (g == 0) {
        *(f4*)(&red[wid][0][4 * c16]) = Wv0;
        *(f4*)(&red[wid][1][4 * c16]) = Wv1;
        *(f4*)(&red[wid][2][4 * c16]) = Wm0;
        *(f4*)(&red[wid][3][4 * c16]) = Wm1;
    }
    // same-wave LDS write->read; lgkmcnt ordering handled by compiler.

    const float* wmA = &red[wid][2][0];
    const float* wmB = &red[wid][3][0];
    float acc0 = 0.f, acc1 = 0.f;
#pragma unroll 4
    for (int a = 0; a < 64; a += 2) {
        acc0 += wmA[a] * we[a * 128 + lane]      + wmA[a + 1] * we[(a + 1) * 128 + lane];
        acc1 += wmB[a] * we[a * 128 + 64 + lane] + wmB[a + 1] * we[(a + 1) * 128 + 64 + lane];
    }
#pragma unroll
    for (int j = 0; j < 20; j++) {
        float sfj = selff[n * 20 + j];
        acc0 += S0 * sfj * we[(64 + j) * 128 + lane];
        acc1 += S1 * sfj * we[(64 + j) * 128 + 64 + lane];
    }
    float o0 = (red[wid][0][lane] + acc0) / (S0 + 1e-16f);
    float o1 = (red[wid][1][lane] + acc1) / (S1 + 1e-16f);
    outb[n * 64 + lane] = 0.5f * (o0 + o1) + skipf[n * 64 + lane];
}

// ---------------------------------------------------------------- final MLP + split outputs
__global__ __launch_bounds__(64) void k_final(
    const float* __restrict__ outb,
    const float* __restrict__ hw1T, const float* __restrict__ hb1,
    const float* __restrict__ hw2T, const float* __restrict__ hb2,
    const float* __restrict__ hw3T, const float* __restrict__ hb3,
    float* __restrict__ out)
{
    __shared__ float ul[64 * 65];
    int lane = threadIdx.x;
    int n = blockIdx.x * 64 + lane;
    bool ok = (n < NN);
    int nn = ok ? n : (NN - 1);

    float h[64];
#pragma unroll
    for (int k = 0; k < 64; k++) h[k] = outb[nn * 64 + k];

    for (int c = 0; c < 64; c++) {
        float a0 = hb1[c], a1 = 0.f, a2 = 0.f, a3 = 0.f;
#pragma unroll
        for (int k = 0; k < 64; k += 4) {
            a0 += h[k]     * hw1T[c * 64 + k];
            a1 += h[k + 1] * hw1T[c * 64 + k + 1];
            a2 += h[k + 2] * hw1T[c * 64 + k + 2];
            a3 += h[k + 3] * hw1T[c * 64 + k + 3];
        }
        ul[c * 65 + lane] = fmaxf((a0 + a1) + (a2 + a3), 0.f);
    }
#pragma unroll
    for (int k = 0; k < 64; k++) h[k] = ul[k * 65 + lane];

    for (int c = 0; c < 64; c++) {
        float a0 = hb2[c], a1 = 0.f, a2 = 0.f, a3 = 0.f;
#pragma unroll
        for (int k = 0; k < 64; k += 4) {
            a0 += h[k]     * hw2T[c * 64 + k];
            a1 += h[k + 1] * hw2T[c * 64 + k + 1];
            a2 += h[k + 2] * hw2T[c * 64 + k + 2];
            a3 += h[k + 3] * hw2T[c * 64 + k + 3];
        }
        ul[c * 65 + lane] = fmaxf((a0 + a1) + (a2 + a3), 0.f);
    }
#pragma unroll
    for (int k = 0; k < 64; k++) h[k] = ul[k * 65 + lane];

    for (int c = 0; c < 20; c++) {
        float a0 = hb3[c], a1 = 0.f, a2 = 0.f, a3 = 0.f;
#pragma unroll
        for (int k = 0; k < 64; k += 4) {
            a0 += h[k]     * hw3T[c * 64 + k];
            a1 += h[k + 1] * hw3T[c * 64 + k + 1];
            a2 += h[k + 2] * hw3T[c * 64 + k + 2];
            a3 += h[k + 3] * hw3T[c * 64 + k + 3];
        }
        float upd = (a0 + a1) + (a2 + a3);
        if (ok) {
            if (c < 2)       out[n * 2 + c] = upd;
            else if (c == 2) out[2 * NN + n] = upd;
            else if (c < 19) out[3 * NN + n * 16 + (c - 3)] = upd;
            else             out[19 * NN + n] = upd;
        }
    }
}

// ---------------------------------------------------------------- launch
extern "C" void kernel_launch(void* const* d_in, const int* in_sizes, int n_in,
                              void* d_out, int out_size, void* d_ws, size_t ws_size,
                              hipStream_t stream)
{
    const float* x      = (const float*)d_in[0];
    const float* angle  = (const float*)d_in[1];
    const float* mol    = (const float*)d_in[2];
    const float* gen    = (const float*)d_in[3];
    const int*   src    = (const int*)d_in[4];
    const int*   dst    = (const int*)d_in[5];
    const float* mask   = (const float*)d_in[6];
    const float* mw1    = (const float*)d_in[7];
    const float* mb1    = (const float*)d_in[8];
    const float* mw2    = (const float*)d_in[9];
    const float* mb2    = (const float*)d_in[10];
    const float* mw3    = (const float*)d_in[11];
    const float* mb3    = (const float*)d_in[12];
    const float* wq     = (const float*)d_in[13];
    const float* bq     = (const float*)d_in[14];
    const float* wk     = (const float*)d_in[15];
    const float* bk     = (const float*)d_in[16];
    const float* wv     = (const float*)d_in[17];
    const float* bv     = (const float*)d_in[18];
    const float* we     = (const float*)d_in[19];
    const float* wskip  = (const float*)d_in[20];
    const float* bskip  = (const float*)d_in[21];
    const float* hw1    = (const float*)d_in[22];
    const float* hb1    = (const float*)d_in[23];
    const float* hw2    = (const float*)d_in[24];
    const float* hb2    = (const float*)d_in[25];
    const float* hw3    = (const float*)d_in[26];
    const float* hb3    = (const float*)d_in[27];
    float* out = (float*)d_out;

    char* p = (char*)d_ws;
    auto alloc = [&](size_t bytes) -> void* {
        void* r = (void*)p;
        p += (bytes + 255) & ~(size_t)255;
        return r;
    };
    int*   row_off = (int*)alloc((NN + 1) * 4);
    float* selff   = (float*)alloc((size_t)NN * 20 * 4);
    float* qf      = (float*)alloc((size_t)NN * 128 * 4);
    float* kf      = (float*)alloc((size_t)NN * 128 * 4);
    float* vf      = (float*)alloc((size_t)NN * 128 * 4);
    float* skipf   = (float*)alloc((size_t)NN * 64 * 4);
    float* qwe     = (float*)alloc((size_t)NN * 168 * 4);
    float* outb    = (float*)alloc((size_t)NN * 64 * 4);
    __hip_bfloat16* W1b = (__hip_bfloat16*)alloc(2048 * 2);
    __hip_bfloat16* W2b = (__hip_bfloat16*)alloc(4096 * 2);
    __hip_bfloat16* W3b = (__hip_bfloat16*)alloc(4096 * 2);
    float* hw1T    = (float*)alloc(4096 * 4);
    float* hw2T    = (float*)alloc(4096 * 4);
    float* hw3T    = (float*)alloc(1280 * 4);
    float* weT     = (float*)alloc(10752 * 4);
    __hip_bfloat16* msg = (__hip_bfloat16*)alloc((size_t)EF * 64 * 2);

    k_prep<<<119, 256, 0, stream>>>(mw1, mb1, mw2, mw3, hw1, hw2, hw3, we,
                                    W1b, W2b, W3b, hw1T, hw2T, hw3T, weT);
    k_csr<<<(NN + 256) / 256, 256, 0, stream>>>(dst, mask, row_off);
    k_node<<<NN / 4, 256, 0, stream>>>(angle, mol, gen, row_off, wq, bq, wk, bk, wv, bv,
                                       wskip, bskip, weT, selff, qf, kf, vf, skipf, qwe);
    k_edge_mfma<<<EF / 64, 64, 0, stream>>>(x, angle, mol, src, dst,
                                            W1b, W2b, W3b, mb2, mb3, msg);
    k_attn<<<NN / 4, 256, 0, stream>>>(row_off, src, msg, qf, kf, vf,
                                       qwe, selff, skipf, we, outb);
    k_final<<<(NN + 63) / 64, 64, 0, stream>>>(outb, hw1T, hb1, hw2T, hb2, hw3T, hb3, out);
}

// Round 4
// 241.181 us; speedup vs baseline: 5.0743x; 1.4372x over previous
//
#include <hip/hip_runtime.h>
#include <hip/hip_bf16.h>
#include <math.h>

#define NN 20000
#define EF 720000

typedef float  f4 __attribute__((ext_vector_type(4)));
typedef unsigned int u4 __attribute__((ext_vector_type(4)));

__device__ __forceinline__ void MFMA(f4& c, u4 a, u4 b) {
    asm("v_mfma_f32_16x16x32_bf16 %0, %1, %2, %0" : "+v"(c) : "v"(a), "v"(b));
}

__device__ __forceinline__ unsigned pk(float a, float b) {
    __hip_bfloat162 t = __halves2bfloat162(__float2bfloat16(a), __float2bfloat16(b));
    unsigned u; __builtin_memcpy(&u, &t, 4); return u;
}
__device__ __forceinline__ float bf2f(unsigned short u) {
    return __builtin_bit_cast(float, (unsigned)u << 16);
}
__device__ __forceinline__ float dot4(f4 a, f4 b) {
    return a.x * b.x + a.y * b.y + a.z * b.z + a.w * b.w;
}
__device__ __forceinline__ void fma4(f4& acc, float w, f4 v) {
    acc.x += w * v.x; acc.y += w * v.y; acc.z += w * v.z; acc.w += w * v.w;
}

// ---------------------------------------------------------------- prep: bf16 weights + transposes
__global__ __launch_bounds__(256) void k_prep(
    const float* __restrict__ mw1, const float* __restrict__ mb1,
    const float* __restrict__ mw2, const float* __restrict__ mw3,
    const float* __restrict__ hw1, const float* __restrict__ hw2, const float* __restrict__ hw3,
    const float* __restrict__ we,
    __hip_bfloat16* __restrict__ W1b, __hip_bfloat16* __restrict__ W2b, __hip_bfloat16* __restrict__ W3b,
    __hip_bfloat16* __restrict__ H1b, __hip_bfloat16* __restrict__ H2b, __hip_bfloat16* __restrict__ H3b,
    float* __restrict__ weT)
{
    int t = blockIdx.x * 256 + threadIdx.x;
    if (t < 2048) {  // W1b[ch][k], K=32: k<21 weights, k==21 bias, rest 0
        int ch = t >> 5, k = t & 31;
        float v = (k < 21) ? mw1[k * 64 + ch] : (k == 21 ? mb1[ch] : 0.f);
        W1b[t] = __float2bfloat16(v); return;
    }
    t -= 2048;
    if (t < 4096) { int ch = t >> 6, k = t & 63; W2b[t] = __float2bfloat16(mw2[k * 64 + ch]); return; }
    t -= 4096;
    if (t < 4096) { int ch = t >> 6, k = t & 63; W3b[t] = __float2bfloat16(mw3[k * 64 + ch]); return; }
    t -= 4096;
    if (t < 4096) { int ch = t >> 6, k = t & 63; H1b[t] = __float2bfloat16(hw1[k * 64 + ch]); return; }
    t -= 4096;
    if (t < 4096) { int ch = t >> 6, k = t & 63; H2b[t] = __float2bfloat16(hw2[k * 64 + ch]); return; }
    t -= 4096;
    if (t < 2048) {  // H3b padded to 32 rows
        int ch = t >> 6, k = t & 63;
        float v = (ch < 20) ? hw3[k * 20 + ch] : 0.f;
        H3b[t] = __float2bfloat16(v); return;
    }
    t -= 2048;
    if (t < 10752) { int cf = t / 84, a = t % 84; weT[t] = we[a * 128 + cf]; return; }
}

// ---------------------------------------------------------------- CSR via binary search
__global__ __launch_bounds__(256) void k_csr(
    const int* __restrict__ dst, const float* __restrict__ mask, int* __restrict__ row_off)
{
    int n = blockIdx.x * 256 + threadIdx.x;
    if (n > NN) return;
    int lo = 0, hi = EF;
    while (lo < hi) { int mid = (lo + hi) >> 1; if (mask[mid] > 0.5f) lo = mid + 1; else hi = mid; }
    int Ea = lo;
    lo = 0; hi = Ea;
    while (lo < hi) { int mid = (lo + hi) >> 1; if (dst[mid] < n) lo = mid + 1; else hi = mid; }
    row_off[n] = lo;
}

// ---------------------------------------------------------------- node features + projections + qwe
__global__ __launch_bounds__(256) void k_node(
    const float* __restrict__ angle, const float* __restrict__ mol, const float* __restrict__ gen,
    const int* __restrict__ row_off,
    const float* __restrict__ wq, const float* __restrict__ bq,
    const float* __restrict__ wk, const float* __restrict__ bk,
    const float* __restrict__ wv, const float* __restrict__ bv,
    const float* __restrict__ wskip, const float* __restrict__ bskip,
    const float* __restrict__ weT,
    float* __restrict__ selff, float* __restrict__ qf, float* __restrict__ kf,
    float* __restrict__ vf, float* __restrict__ skipf, float* __restrict__ qwe)
{
    __shared__ float qlds[4 * 128];
    int wid = threadIdx.x >> 6, lane = threadIdx.x & 63;
    int n = blockIdx.x * 4 + wid;

    float an = angle[n];
    float sv, cv; sincosf(an, &sv, &cv);
    float degf = (float)(row_off[n + 1] - row_off[n]);
    float sf[20];
    sf[0] = sv; sf[1] = cv;
#pragma unroll
    for (int j = 0; j < 16; j++) sf[2 + j] = mol[n * 16 + j];
    sf[18] = gen[n];
    sf[19] = degf;

    float sval = (lane == 0) ? sv : (lane == 1) ? cv :
                 (lane < 18) ? mol[n * 16 + (lane - 2)] :
                 (lane == 18) ? gen[n] : degf;
    if (lane < 20) selff[n * 20 + lane] = sval;

    float q0 = bq[lane], q1 = bq[64 + lane];
    float k0 = bk[lane], k1 = bk[64 + lane];
    float v0 = bv[lane], v1 = bv[64 + lane];
    float sk = bskip[lane];
#pragma unroll
    for (int a = 0; a < 20; a++) {
        float s = sf[a];
        q0 += s * wq[a * 128 + lane];      q1 += s * wq[a * 128 + 64 + lane];
        k0 += s * wk[a * 128 + lane];      k1 += s * wk[a * 128 + 64 + lane];
        v0 += s * wv[a * 128 + lane];      v1 += s * wv[a * 128 + 64 + lane];
        sk += s * wskip[a * 64 + lane];
    }
    qf[n * 128 + lane] = q0; qf[n * 128 + 64 + lane] = q1;
    kf[n * 128 + lane] = k0; kf[n * 128 + 64 + lane] = k1;
    vf[n * 128 + lane] = v0; vf[n * 128 + 64 + lane] = v1;
    skipf[n * 64 + lane] = sk;
    qlds[wid * 128 + lane] = q0; qlds[wid * 128 + 64 + lane] = q1;
    __syncthreads();

#pragma unroll
    for (int r = 0; r < 3; r++) {
        int o = r * 64 + lane;
        if (o < 168) {
            int h = (o >= 84) ? 1 : 0;
            int a = o - 84 * h;
            float acc = 0.f, acc2 = 0.f;
#pragma unroll
            for (int c = 0; c < 64; c += 2) {
                acc  += qlds[wid * 128 + h * 64 + c]     * weT[(h * 64 + c) * 84 + a];
                acc2 += qlds[wid * 128 + h * 64 + c + 1] * weT[(h * 64 + c + 1) * 84 + a];
            }
            qwe[n * 168 + o] = acc + acc2;
        }
    }
}

// ---------------------------------------------------------------- edge MLP via MFMA (1 wave = 64 edges)
__device__ __forceinline__ void write_tiles(char* lds, int l, f4 (&acc)[4][4], const float* bias)
{
#pragma unroll
    for (int m = 0; m < 4; m++) {
        f4 bv;
        if (bias) bv = *(const f4*)(bias + m * 16 + ((l >> 4) << 2));
        else      { bv.x = 0.f; bv.y = 0.f; bv.z = 0.f; bv.w = 0.f; }
#pragma unroll
        for (int n = 0; n < 4; n++) {
            f4 v = acc[m][n];
            float v0 = fmaxf(v.x + bv.x, 0.f);
            float v1 = fmaxf(v.y + bv.y, 0.f);
            float v2 = fmaxf(v.z + bv.z, 0.f);
            float v3 = fmaxf(v.w + bv.w, 0.f);
            int e   = n * 16 + (l & 15);
            int ch0 = m * 16 + ((l >> 4) << 2);
            int byte = e * 128 + ((((ch0 >> 3) ^ (e & 7))) << 4) + (ch0 & 7) * 2;
            uint2 w; w.x = pk(v0, v1); w.y = pk(v2, v3);
            *(uint2*)(lds + byte) = w;
        }
    }
}

__global__ __launch_bounds__(64) void k_edge_mfma(
    const float* __restrict__ x, const float* __restrict__ angle, const float* __restrict__ mol,
    const int* __restrict__ src, const int* __restrict__ dst,
    const __hip_bfloat16* __restrict__ W1b, const __hip_bfloat16* __restrict__ W2b,
    const __hip_bfloat16* __restrict__ W3b,
    const float* __restrict__ mb2, const float* __restrict__ mb3,
    __hip_bfloat16* __restrict__ msg)
{
    __shared__ char lds[64 * 128];
    int l = threadIdx.x;
    int e0 = blockIdx.x * 64;

    int s = src[e0 + l], d = dst[e0 + l];
    float2 xs = ((const float2*)x)[s], xd = ((const float2*)x)[d];
    float dx = xs.x - xd.x, dy = xs.y - xd.y;
    float r = sqrtf(fmaxf(dx * dx + dy * dy, 1e-12f));
    float da = angle[s] - angle[d];
    float sv, cv; sincosf(da, &sv, &cv);
    const float4* m4 = (const float4*)mol;
    float4 sa = m4[s * 4 + 0], sb = m4[s * 4 + 1], sc = m4[s * 4 + 2], sd = m4[s * 4 + 3];
    float4 ta = m4[d * 4 + 0], tb = m4[d * 4 + 1], tc = m4[d * 4 + 2], td = m4[d * 4 + 3];
    float f[22];
    f[0] = dx; f[1] = dy; f[2] = r; f[3] = sv; f[4] = cv;
    f[5]  = sa.x - ta.x; f[6]  = sa.y - ta.y; f[7]  = sa.z - ta.z; f[8]  = sa.w - ta.w;
    f[9]  = sb.x - tb.x; f[10] = sb.y - tb.y; f[11] = sb.z - tb.z; f[12] = sb.w - tb.w;
    f[13] = sc.x - tc.x; f[14] = sc.y - tc.y; f[15] = sc.z - tc.z; f[16] = sc.w - tc.w;
    f[17] = sd.x - td.x; f[18] = sd.y - td.y; f[19] = sd.z - td.z; f[20] = sd.w - td.w;
    f[21] = 1.f;
    unsigned p[16];
#pragma unroll
    for (int j = 0; j < 11; j++) p[j] = pk(f[2 * j], f[2 * j + 1]);
#pragma unroll
    for (int j = 11; j < 16; j++) p[j] = 0u;
#pragma unroll
    for (int g = 0; g < 4; g++) {
        int byte = l * 64 + ((g ^ (l & 3)) << 4);
        u4 w; w.x = p[4 * g]; w.y = p[4 * g + 1]; w.z = p[4 * g + 2]; w.w = p[4 * g + 3];
        *(u4*)(lds + byte) = w;
    }
    __syncthreads();

    u4 B1[4];
#pragma unroll
    for (int n = 0; n < 4; n++) {
        int e = n * 16 + (l & 15);
        int byte = e * 64 + ((((l >> 4) & 3) ^ (e & 3)) << 4);
        B1[n] = *(const u4*)(lds + byte);
    }
    __syncthreads();

    f4 acc[4][4];
#pragma unroll
    for (int m = 0; m < 4; m++)
#pragma unroll
        for (int n = 0; n < 4; n++) { acc[m][n].x = 0.f; acc[m][n].y = 0.f; acc[m][n].z = 0.f; acc[m][n].w = 0.f; }

    const unsigned short* W1u = (const unsigned short*)W1b;
    const unsigned short* W2u = (const unsigned short*)W2b;
    const unsigned short* W3u = (const unsigned short*)W3b;
#pragma unroll
    for (int m = 0; m < 4; m++) {
        u4 w = *(const u4*)(W1u + (m * 16 + (l & 15)) * 32 + (l >> 4) * 8);
#pragma unroll
        for (int n = 0; n < 4; n++) MFMA(acc[m][n], w, B1[n]);
    }
    write_tiles(lds, l, acc, nullptr);
    __syncthreads();

    u4 B2[4][2];
#pragma unroll
    for (int n = 0; n < 4; n++)
#pragma unroll
        for (int ks = 0; ks < 2; ks++) {
            int e = n * 16 + (l & 15);
            int g = ks * 4 + (l >> 4);
            B2[n][ks] = *(const u4*)(lds + e * 128 + ((g ^ (e & 7)) << 4));
        }
    __syncthreads();
#pragma unroll
    for (int m = 0; m < 4; m++)
#pragma unroll
        for (int n = 0; n < 4; n++) { acc[m][n].x = 0.f; acc[m][n].y = 0.f; acc[m][n].z = 0.f; acc[m][n].w = 0.f; }
#pragma unroll
    for (int m = 0; m < 4; m++)
#pragma unroll
        for (int ks = 0; ks < 2; ks++) {
            u4 w = *(const u4*)(W2u + (m * 16 + (l & 15)) * 64 + ks * 32 + (l >> 4) * 8);
#pragma unroll
            for (int n = 0; n < 4; n++) MFMA(acc[m][n], w, B2[n][ks]);
        }
    write_tiles(lds, l, acc, mb2);
    __syncthreads();

#pragma unroll
    for (int n = 0; n < 4; n++)
#pragma unroll
        for (int ks = 0; ks < 2; ks++) {
            int e = n * 16 + (l & 15);
            int g = ks * 4 + (l >> 4);
            B2[n][ks] = *(const u4*)(lds + e * 128 + ((g ^ (e & 7)) << 4));
        }
    __syncthreads();
#pragma unroll
    for (int m = 0; m < 4; m++)
#pragma unroll
        for (int n = 0; n < 4; n++) { acc[m][n].x = 0.f; acc[m][n].y = 0.f; acc[m][n].z = 0.f; acc[m][n].w = 0.f; }
#pragma unroll
    for (int m = 0; m < 4; m++)
#pragma unroll
        for (int ks = 0; ks < 2; ks++) {
            u4 w = *(const u4*)(W3u + (m * 16 + (l & 15)) * 64 + ks * 32 + (l >> 4) * 8);
#pragma unroll
            for (int n = 0; n < 4; n++) MFMA(acc[m][n], w, B2[n][ks]);
        }
    write_tiles(lds, l, acc, mb3);
    __syncthreads();

#pragma unroll
    for (int it = 0; it < 8; it++) {
        int e = it * 8 + (l >> 3);
        int g = l & 7;
        u4 vv = *(const u4*)(lds + e * 128 + ((g ^ (e & 7)) << 4));
        *(u4*)((unsigned short*)msg + (size_t)(e0 + e) * 64 + g * 8) = vv;
    }
}

// ---------------------------------------------------------------- attention aggregate
__global__ __launch_bounds__(256) void k_attn(
    const int* __restrict__ row_off, const int* __restrict__ src,
    const __hip_bfloat16* __restrict__ msg,
    const float* __restrict__ qf, const float* __restrict__ kf, const float* __restrict__ vf,
    const float* __restrict__ qwe, const float* __restrict__ selff, const float* __restrict__ skipf,
    const float* __restrict__ we,
    float* __restrict__ outb)
{
    __shared__ float red[4][4][64];
    int tid = threadIdx.x, wid = tid >> 6, lane = tid & 63;
    int g = lane >> 4, c16 = lane & 15;
    int n = blockIdx.x * 4 + wid;

    const f4* q4 = (const f4*)(qf + n * 128);
    f4 q0 = q4[c16], q1 = q4[16 + c16];
    f4 qm0 = *(const f4*)(qwe + n * 168 + 4 * c16);
    f4 qm1 = *(const f4*)(qwe + n * 168 + 84 + 4 * c16);

    float a00 = 0.f, a01 = 0.f;
#pragma unroll
    for (int j = 0; j < 20; j++) {
        float sfj = selff[n * 20 + j];
        a00 += sfj * qwe[n * 168 + 64 + j];
        a01 += sfj * qwe[n * 168 + 84 + 64 + j];
    }

    const unsigned short* msgu = (const unsigned short*)msg;
    int r0 = row_off[n], r1 = row_off[n + 1];
    int nit = (r1 - r0 + 3) >> 2;

    f4 Wv0 = {0,0,0,0}, Wv1 = {0,0,0,0}, Wm0 = {0,0,0,0}, Wm1 = {0,0,0,0};
    float S0 = 0.f, S1 = 0.f;

#pragma unroll 2
    for (int it = 0; it < nit; it++) {
        int e = r0 + it * 4 + g;
        bool ok = (e < r1);
        int ec = ok ? e : r0;
        int s = src[ec];
        const f4* kp = (const f4*)(kf + s * 128);
        const f4* vp = (const f4*)(vf + s * 128);
        f4 k0 = kp[c16], k1 = kp[16 + c16];
        f4 v0 = vp[c16], v1 = vp[16 + c16];
        ushort4 mu = *(const ushort4*)(msgu + (size_t)ec * 64 + 4 * c16);
        f4 mc; mc.x = bf2f(mu.x); mc.y = bf2f(mu.y); mc.z = bf2f(mu.z); mc.w = bf2f(mu.w);

        float t0 = dot4(q0, k0) + dot4(qm0, mc);
        float t1 = dot4(q1, k1) + dot4(qm1, mc);
#pragma unroll
        for (int mk = 1; mk < 16; mk <<= 1) {
            t0 += __shfl_xor(t0, mk, 64);
            t1 += __shfl_xor(t1, mk, 64);
        }
        float w0 = ok ? __expf((t0 + a00) * 0.125f) : 0.f;
        float w1 = ok ? __expf((t1 + a01) * 0.125f) : 0.f;
        S0 += w0; S1 += w1;
        fma4(Wv0, w0, v0); fma4(Wv1, w1, v1);
        fma4(Wm0, w0, mc); fma4(Wm1, w1, mc);
    }

#pragma unroll
    for (int mk = 16; mk <= 32; mk <<= 1) {
        Wv0.x += __shfl_xor(Wv0.x, mk, 64); Wv0.y += __shfl_xor(Wv0.y, mk, 64);
        Wv0.z += __shfl_xor(Wv0.z, mk, 64); Wv0.w += __shfl_xor(Wv0.w, mk, 64);
        Wv1.x += __shfl_xor(Wv1.x, mk, 64); Wv1.y += __shfl_xor(Wv1.y, mk, 64);
        Wv1.z += __shfl_xor(Wv1.z, mk, 64); Wv1.w += __shfl_xor(Wv1.w, mk, 64);
        Wm0.x += __shfl_xor(Wm0.x, mk, 64); Wm0.y += __shfl_xor(Wm0.y, mk, 64);
        Wm0.z += __shfl_xor(Wm0.z, mk, 64); Wm0.w += __shfl_xor(Wm0.w, mk, 64);
        Wm1.x += __shfl_xor(Wm1.x, mk, 64); Wm1.y += __shfl_xor(Wm1.y, mk, 64);
        Wm1.z += __shfl_xor(Wm1.z, mk, 64); Wm1.w += __shfl_xor(Wm1.w, mk, 64);
        S0 += __shfl_xor(S0, mk, 64); S1 += __shfl_xor(S1, mk, 64);
    }

    if (g == 0) {
        *(f4*)(&red[wid][0][4 * c16]) = Wv0;
        *(f4*)(&red[wid][1][4 * c16]) = Wv1;
        *(f4*)(&red[wid][2][4 * c16]) = Wm0;
        *(f4*)(&red[wid][3][4 * c16]) = Wm1;
    }

    const float* wmA = &red[wid][2][0];
    const float* wmB = &red[wid][3][0];
    float acc0 = 0.f, acc1 = 0.f;
#pragma unroll 4
    for (int a = 0; a < 64; a += 2) {
        acc0 += wmA[a] * we[a * 128 + lane]      + wmA[a + 1] * we[(a + 1) * 128 + lane];
        acc1 += wmB[a] * we[a * 128 + 64 + lane] + wmB[a + 1] * we[(a + 1) * 128 + 64 + lane];
    }
#pragma unroll
    for (int j = 0; j < 20; j++) {
        float sfj = selff[n * 20 + j];
        acc0 += S0 * sfj * we[(64 + j) * 128 + lane];
        acc1 += S1 * sfj * we[(64 + j) * 128 + 64 + lane];
    }
    float o0 = (red[wid][0][lane] + acc0) / (S0 + 1e-16f);
    float o1 = (red[wid][1][lane] + acc1) / (S1 + 1e-16f);
    outb[n * 64 + lane] = 0.5f * (o0 + o1) + skipf[n * 64 + lane];
}

// ---------------------------------------------------------------- final MLP via MFMA (1 wave = 64 nodes)
__global__ __launch_bounds__(64) void k_final_mfma(
    const float* __restrict__ outb,
    const __hip_bfloat16* __restrict__ H1b, const __hip_bfloat16* __restrict__ H2b,
    const __hip_bfloat16* __restrict__ H3b,
    const float* __restrict__ hb1, const float* __restrict__ hb2, const float* __restrict__ hb3,
    float* __restrict__ out)
{
    __shared__ char lds[64 * 128];
    int l = threadIdx.x;
    int n0 = blockIdx.x * 64;
    int nl = n0 + l;
    int nn = (nl < NN) ? nl : (NN - 1);

    // stage outb row -> LDS bf16, layout [node][k] with XOR swizzle (K=64)
    const float* row = outb + (size_t)nn * 64;
#pragma unroll
    for (int g = 0; g < 8; g++) {
        u4 w;
        w.x = pk(row[8 * g + 0], row[8 * g + 1]);
        w.y = pk(row[8 * g + 2], row[8 * g + 3]);
        w.z = pk(row[8 * g + 4], row[8 * g + 5]);
        w.w = pk(row[8 * g + 6], row[8 * g + 7]);
        *(u4*)(lds + l * 128 + ((g ^ (l & 7)) << 4)) = w;
    }
    __syncthreads();

    const unsigned short* H1u = (const unsigned short*)H1b;
    const unsigned short* H2u = (const unsigned short*)H2b;
    const unsigned short* H3u = (const unsigned short*)H3b;

    u4 B[4][2];
    f4 acc[4][4];

    // ---- stage 1: 64 -> 64 (relu, +hb1)
#pragma unroll
    for (int n = 0; n < 4; n++)
#pragma unroll
        for (int ks = 0; ks < 2; ks++) {
            int e = n * 16 + (l & 15);
            int g = ks * 4 + (l >> 4);
            B[n][ks] = *(const u4*)(lds + e * 128 + ((g ^ (e & 7)) << 4));
        }
    __syncthreads();
#pragma unroll
    for (int m = 0; m < 4; m++)
#pragma unroll
        for (int n = 0; n < 4; n++) { acc[m][n].x = 0.f; acc[m][n].y = 0.f; acc[m][n].z = 0.f; acc[m][n].w = 0.f; }
#pragma unroll
    for (int m = 0; m < 4; m++)
#pragma unroll
        for (int ks = 0; ks < 2; ks++) {
            u4 w = *(const u4*)(H1u + (m * 16 + (l & 15)) * 64 + ks * 32 + (l >> 4) * 8);
#pragma unroll
            for (int n = 0; n < 4; n++) MFMA(acc[m][n], w, B[n][ks]);
        }
    write_tiles(lds, l, acc, hb1);
    __syncthreads();

    // ---- stage 2: 64 -> 64 (relu, +hb2)
#pragma unroll
    for (int n = 0; n < 4; n++)
#pragma unroll
        for (int ks = 0; ks < 2; ks++) {
            int e = n * 16 + (l & 15);
            int g = ks * 4 + (l >> 4);
            B[n][ks] = *(const u4*)(lds + e * 128 + ((g ^ (e & 7)) << 4));
        }
    __syncthreads();
#pragma unroll
    for (int m = 0; m < 4; m++)
#pragma unroll
        for (int n = 0; n < 4; n++) { acc[m][n].x = 0.f; acc[m][n].y = 0.f; acc[m][n].z = 0.f; acc[m][n].w = 0.f; }
#pragma unroll
    for (int m = 0; m < 4; m++)
#pragma unroll
        for (int ks = 0; ks < 2; ks++) {
            u4 w = *(const u4*)(H2u + (m * 16 + (l & 15)) * 64 + ks * 32 + (l >> 4) * 8);
#pragma unroll
            for (int n = 0; n < 4; n++) MFMA(acc[m][n], w, B[n][ks]);
        }
    write_tiles(lds, l, acc, hb2);
    __syncthreads();

    // ---- stage 3: 64 -> 20 (+hb3), direct scattered store
#pragma unroll
    for (int n = 0; n < 4; n++)
#pragma unroll
        for (int ks = 0; ks < 2; ks++) {
            int e = n * 16 + (l & 15);
            int g = ks * 4 + (l >> 4);
            B[n][ks] = *(const u4*)(lds + e * 128 + ((g ^ (e & 7)) << 4));
        }

    f4 acc3[2][4];
#pragma unroll
    for (int m = 0; m < 2; m++)
#pragma unroll
        for (int n = 0; n < 4; n++) { acc3[m][n].x = 0.f; acc3[m][n].y = 0.f; acc3[m][n].z = 0.f; acc3[m][n].w = 0.f; }
#pragma unroll
    for (int m = 0; m < 2; m++)
#pragma unroll
        for (int ks = 0; ks < 2; ks++) {
            u4 w = *(const u4*)(H3u + (m * 16 + (l & 15)) * 64 + ks * 32 + (l >> 4) * 8);
#pragma unroll
            for (int n = 0; n < 4; n++) MFMA(acc3[m][n], w, B[n][ks]);
        }

    int r0 = (l >> 4) * 2;  // pairs: reg rows base/2
#pragma unroll
    for (int m = 0; m < 2; m++) {
#pragma unroll
        for (int j = 0; j < 4; j++) {
            int ch = m * 16 + (l >> 4) * 4 + j;
            if (ch < 20) {
                float b = hb3[ch];
#pragma unroll
                for (int nt = 0; nt < 4; nt++) {
                    int node = n0 + nt * 16 + (l & 15);
                    if (node < NN) {
                        float v = acc3[m][nt][j] + b;
                        if (ch < 2)       out[node * 2 + ch] = v;
                        else if (ch == 2) out[2 * NN + node] = v;
                        else if (ch < 19) out[3 * NN + node * 16 + (ch - 3)] = v;
                        else              out[19 * NN + node] = v;
                    }
                }
            }
        }
    }
    (void)r0;
}

// ---------------------------------------------------------------- launch
extern "C" void kernel_launch(void* const* d_in, const int* in_sizes, int n_in,
                              void* d_out, int out_size, void* d_ws, size_t ws_size,
                              hipStream_t stream)
{
    const float* x      = (const float*)d_in[0];
    const float* angle  = (const float*)d_in[1];
    const float* mol    = (const float*)d_in[2];
    const float* gen    = (const float*)d_in[3];
    const int*   src    = (const int*)d_in[4];
    const int*   dst    = (const int*)d_in[5];
    const float* mask   = (const float*)d_in[6];
    const float* mw1    = (const float*)d_in[7];
    const float* mb1    = (const float*)d_in[8];
    const float* mw2    = (const float*)d_in[9];
    const float* mb2    = (const float*)d_in[10];
    const float* mw3    = (const float*)d_in[11];
    const float* mb3    = (const float*)d_in[12];
    const float* wq     = (const float*)d_in[13];
    const float* bq     = (const float*)d_in[14];
    const float* wk     = (const float*)d_in[15];
    const float* bk     = (const float*)d_in[16];
    const float* wv     = (const float*)d_in[17];
    const float* bv     = (const float*)d_in[18];
    const float* we     = (const float*)d_in[19];
    const float* wskip  = (const float*)d_in[20];
    const float* bskip  = (const float*)d_in[21];
    const float* hw1    = (const float*)d_in[22];
    const float* hb1    = (const float*)d_in[23];
    const float* hw2    = (const float*)d_in[24];
    const float* hb2    = (const float*)d_in[25];
    const float* hw3    = (const float*)d_in[26];
    const float* hb3    = (const float*)d_in[27];
    float* out = (float*)d_out;

    char* p = (char*)d_ws;
    auto alloc = [&](size_t bytes) -> void* {
        void* r = (void*)p;
        p += (bytes + 255) & ~(size_t)255;
        return r;
    };
    int*   row_off = (int*)alloc((NN + 1) * 4);
    float* selff   = (float*)alloc((size_t)NN * 20 * 4);
    float* qf      = (float*)alloc((size_t)NN * 128 * 4);
    float* kf      = (float*)alloc((size_t)NN * 128 * 4);
    float* vf      = (float*)alloc((size_t)NN * 128 * 4);
    float* skipf   = (float*)alloc((size_t)NN * 64 * 4);
    float* qwe     = (float*)alloc((size_t)NN * 168 * 4);
    float* outb    = (float*)alloc((size_t)NN * 64 * 4);
    __hip_bfloat16* W1b = (__hip_bfloat16*)alloc(2048 * 2);
    __hip_bfloat16* W2b = (__hip_bfloat16*)alloc(4096 * 2);
    __hip_bfloat16* W3b = (__hip_bfloat16*)alloc(4096 * 2);
    __hip_bfloat16* H1b = (__hip_bfloat16*)alloc(4096 * 2);
    __hip_bfloat16* H2b = (__hip_bfloat16*)alloc(4096 * 2);
    __hip_bfloat16* H3b = (__hip_bfloat16*)alloc(2048 * 2);
    float* weT     = (float*)alloc(10752 * 4);
    __hip_bfloat16* msg = (__hip_bfloat16*)alloc((size_t)EF * 64 * 2);

    k_prep<<<123, 256, 0, stream>>>(mw1, mb1, mw2, mw3, hw1, hw2, hw3, we,
                                    W1b, W2b, W3b, H1b, H2b, H3b, weT);
    k_csr<<<(NN + 256) / 256, 256, 0, stream>>>(dst, mask, row_off);
    k_node<<<NN / 4, 256, 0, stream>>>(angle, mol, gen, row_off, wq, bq, wk, bk, wv, bv,
                                       wskip, bskip, weT, selff, qf, kf, vf, skipf, qwe);
    k_edge_mfma<<<EF / 64, 64, 0, stream>>>(x, angle, mol, src, dst,
                                            W1b, W2b, W3b, mb2, mb3, msg);
    k_attn<<<NN / 4, 256, 0, stream>>>(row_off, src, msg, qf, kf, vf,
                                       qwe, selff, skipf, we, outb);
    k_final_mfma<<<(NN + 63) / 64, 64, 0, stream>>>(outb, H1b, H2b, H3b, hb1, hb2, hb3, out);
}

// Round 5
// 216.475 us; speedup vs baseline: 5.6535x; 1.1141x over previous
//
#include <hip/hip_runtime.h>
#include <hip/hip_bf16.h>
#include <math.h>

#define NN 20000
#define EF 720000

typedef float  f4 __attribute__((ext_vector_type(4)));
typedef unsigned int u4 __attribute__((ext_vector_type(4)));

__device__ __forceinline__ void MFMA(f4& c, u4 a, u4 b) {
    asm("v_mfma_f32_16x16x32_bf16 %0, %1, %2, %0" : "+v"(c) : "v"(a), "v"(b));
}

__device__ __forceinline__ unsigned pk(float a, float b) {
    __hip_bfloat162 t = __halves2bfloat162(__float2bfloat16(a), __float2bfloat16(b));
    unsigned u; __builtin_memcpy(&u, &t, 4); return u;
}
__device__ __forceinline__ float bf2f(unsigned short u) {
    return __builtin_bit_cast(float, (unsigned)u << 16);
}
__device__ __forceinline__ f4 bf2f4(ushort4 u) {
    f4 r; r.x = bf2f(u.x); r.y = bf2f(u.y); r.z = bf2f(u.z); r.w = bf2f(u.w); return r;
}
__device__ __forceinline__ float dot4(f4 a, f4 b) {
    return a.x * b.x + a.y * b.y + a.z * b.z + a.w * b.w;
}
__device__ __forceinline__ void fma4(f4& acc, float w, f4 v) {
    acc.x += w * v.x; acc.y += w * v.y; acc.z += w * v.z; acc.w += w * v.w;
}

// ---------------------------------------------------------------- prep: bf16 weights + transposes
__global__ __launch_bounds__(256) void k_prep(
    const float* __restrict__ mw1, const float* __restrict__ mb1,
    const float* __restrict__ mw2, const float* __restrict__ mw3,
    const float* __restrict__ hw1, const float* __restrict__ hw2, const float* __restrict__ hw3,
    const float* __restrict__ we,
    __hip_bfloat16* __restrict__ W1b, __hip_bfloat16* __restrict__ W2b, __hip_bfloat16* __restrict__ W3b,
    __hip_bfloat16* __restrict__ H1b, __hip_bfloat16* __restrict__ H2b, __hip_bfloat16* __restrict__ H3b,
    float* __restrict__ weT)
{
    int t = blockIdx.x * 256 + threadIdx.x;
    if (t < 2048) {  // W1b[ch][k], K=32: k<21 weights, k==21 bias, rest 0
        int ch = t >> 5, k = t & 31;
        float v = (k < 21) ? mw1[k * 64 + ch] : (k == 21 ? mb1[ch] : 0.f);
        W1b[t] = __float2bfloat16(v); return;
    }
    t -= 2048;
    if (t < 4096) { int ch = t >> 6, k = t & 63; W2b[t] = __float2bfloat16(mw2[k * 64 + ch]); return; }
    t -= 4096;
    if (t < 4096) { int ch = t >> 6, k = t & 63; W3b[t] = __float2bfloat16(mw3[k * 64 + ch]); return; }
    t -= 4096;
    if (t < 4096) { int ch = t >> 6, k = t & 63; H1b[t] = __float2bfloat16(hw1[k * 64 + ch]); return; }
    t -= 4096;
    if (t < 4096) { int ch = t >> 6, k = t & 63; H2b[t] = __float2bfloat16(hw2[k * 64 + ch]); return; }
    t -= 4096;
    if (t < 2048) {  // H3b padded to 32 rows
        int ch = t >> 6, k = t & 63;
        float v = (ch < 20) ? hw3[k * 20 + ch] : 0.f;
        H3b[t] = __float2bfloat16(v); return;
    }
    t -= 2048;
    if (t < 10752) { int cf = t / 84, a = t % 84; weT[t] = we[a * 128 + cf]; return; }
}

// ---------------------------------------------------------------- CSR via binary search
__global__ __launch_bounds__(256) void k_csr(
    const int* __restrict__ dst, const float* __restrict__ mask, int* __restrict__ row_off)
{
    int n = blockIdx.x * 256 + threadIdx.x;
    if (n > NN) return;
    int lo = 0, hi = EF;
    while (lo < hi) { int mid = (lo + hi) >> 1; if (mask[mid] > 0.5f) lo = mid + 1; else hi = mid; }
    int Ea = lo;
    lo = 0; hi = Ea;
    while (lo < hi) { int mid = (lo + hi) >> 1; if (dst[mid] < n) lo = mid + 1; else hi = mid; }
    row_off[n] = lo;
}

// ---------------------------------------------------------------- node features + projections + qwe
// kvf[n][256] bf16: [0..63]=k head0, [64..127]=k head1, [128..191]=v head0, [192..255]=v head1
__global__ __launch_bounds__(256) void k_node(
    const float* __restrict__ angle, const float* __restrict__ mol, const float* __restrict__ gen,
    const int* __restrict__ row_off,
    const float* __restrict__ wq, const float* __restrict__ bq,
    const float* __restrict__ wk, const float* __restrict__ bk,
    const float* __restrict__ wv, const float* __restrict__ bv,
    const float* __restrict__ wskip, const float* __restrict__ bskip,
    const float* __restrict__ weT,
    float* __restrict__ selff, float* __restrict__ qf, __hip_bfloat16* __restrict__ kvf,
    float* __restrict__ skipf, float* __restrict__ qwe)
{
    __shared__ float qlds[4 * 128];
    int wid = threadIdx.x >> 6, lane = threadIdx.x & 63;
    int n = blockIdx.x * 4 + wid;

    float an = angle[n];
    float sv, cv; sincosf(an, &sv, &cv);
    float degf = (float)(row_off[n + 1] - row_off[n]);
    float sf[20];
    sf[0] = sv; sf[1] = cv;
#pragma unroll
    for (int j = 0; j < 16; j++) sf[2 + j] = mol[n * 16 + j];
    sf[18] = gen[n];
    sf[19] = degf;

    float sval = (lane == 0) ? sv : (lane == 1) ? cv :
                 (lane < 18) ? mol[n * 16 + (lane - 2)] :
                 (lane == 18) ? gen[n] : degf;
    if (lane < 20) selff[n * 20 + lane] = sval;

    float q0 = bq[lane], q1 = bq[64 + lane];
    float k0 = bk[lane], k1 = bk[64 + lane];
    float v0 = bv[lane], v1 = bv[64 + lane];
    float sk = bskip[lane];
#pragma unroll
    for (int a = 0; a < 20; a++) {
        float s = sf[a];
        q0 += s * wq[a * 128 + lane];      q1 += s * wq[a * 128 + 64 + lane];
        k0 += s * wk[a * 128 + lane];      k1 += s * wk[a * 128 + 64 + lane];
        v0 += s * wv[a * 128 + lane];      v1 += s * wv[a * 128 + 64 + lane];
        sk += s * wskip[a * 64 + lane];
    }
    qf[n * 128 + lane] = q0; qf[n * 128 + 64 + lane] = q1;
    kvf[n * 256 + lane]       = __float2bfloat16(k0);
    kvf[n * 256 + 64 + lane]  = __float2bfloat16(k1);
    kvf[n * 256 + 128 + lane] = __float2bfloat16(v0);
    kvf[n * 256 + 192 + lane] = __float2bfloat16(v1);
    skipf[n * 64 + lane] = sk;
    qlds[wid * 128 + lane] = q0; qlds[wid * 128 + 64 + lane] = q1;
    __syncthreads();

#pragma unroll
    for (int r = 0; r < 3; r++) {
        int o = r * 64 + lane;
        if (o < 168) {
            int h = (o >= 84) ? 1 : 0;
            int a = o - 84 * h;
            float acc = 0.f, acc2 = 0.f;
#pragma unroll
            for (int c = 0; c < 64; c += 2) {
                acc  += qlds[wid * 128 + h * 64 + c]     * weT[(h * 64 + c) * 84 + a];
                acc2 += qlds[wid * 128 + h * 64 + c + 1] * weT[(h * 64 + c + 1) * 84 + a];
            }
            qwe[n * 168 + o] = acc + acc2;
        }
    }
}

// ---------------------------------------------------------------- edge MLP via MFMA (wave = 64 edges, 4 waves/block)
__device__ __forceinline__ void write_tiles(char* lds, int l, f4 (&acc)[4][4], const float* bias)
{
#pragma unroll
    for (int m = 0; m < 4; m++) {
        f4 bv;
        if (bias) bv = *(const f4*)(bias + m * 16 + ((l >> 4) << 2));
        else      { bv.x = 0.f; bv.y = 0.f; bv.z = 0.f; bv.w = 0.f; }
#pragma unroll
        for (int n = 0; n < 4; n++) {
            f4 v = acc[m][n];
            float v0 = fmaxf(v.x + bv.x, 0.f);
            float v1 = fmaxf(v.y + bv.y, 0.f);
            float v2 = fmaxf(v.z + bv.z, 0.f);
            float v3 = fmaxf(v.w + bv.w, 0.f);
            int e   = n * 16 + (l & 15);
            int ch0 = m * 16 + ((l >> 4) << 2);
            int byte = e * 128 + ((((ch0 >> 3) ^ (e & 7))) << 4) + (ch0 & 7) * 2;
            uint2 w; w.x = pk(v0, v1); w.y = pk(v2, v3);
            *(uint2*)(lds + byte) = w;
        }
    }
}

__global__ __launch_bounds__(256) void k_edge_mfma(
    const float* __restrict__ x, const float* __restrict__ angle, const float* __restrict__ mol,
    const int* __restrict__ src, const int* __restrict__ dst,
    const __hip_bfloat16* __restrict__ W1b, const __hip_bfloat16* __restrict__ W2b,
    const __hip_bfloat16* __restrict__ W3b,
    const float* __restrict__ mb2, const float* __restrict__ mb3,
    __hip_bfloat16* __restrict__ msg)
{
    __shared__ char lds_all[4][64 * 128];
    int wv = threadIdx.x >> 6, l = threadIdx.x & 63;
    char* lds = lds_all[wv];
    int e0 = (blockIdx.x * 4 + wv) * 64;
    if (e0 + 64 > EF) e0 = EF - 64;  // tail waves duplicate an edge range (identical writes, benign)

    int s = src[e0 + l], d = dst[e0 + l];
    float2 xs = ((const float2*)x)[s], xd = ((const float2*)x)[d];
    float dx = xs.x - xd.x, dy = xs.y - xd.y;
    float r = sqrtf(fmaxf(dx * dx + dy * dy, 1e-12f));
    float da = angle[s] - angle[d];
    float sv, cv; sincosf(da, &sv, &cv);
    const float4* m4 = (const float4*)mol;
    float4 sa = m4[s * 4 + 0], sb = m4[s * 4 + 1], sc = m4[s * 4 + 2], sd = m4[s * 4 + 3];
    float4 ta = m4[d * 4 + 0], tb = m4[d * 4 + 1], tc = m4[d * 4 + 2], td = m4[d * 4 + 3];
    float f[22];
    f[0] = dx; f[1] = dy; f[2] = r; f[3] = sv; f[4] = cv;
    f[5]  = sa.x - ta.x; f[6]  = sa.y - ta.y; f[7]  = sa.z - ta.z; f[8]  = sa.w - ta.w;
    f[9]  = sb.x - tb.x; f[10] = sb.y - tb.y; f[11] = sb.z - tb.z; f[12] = sb.w - tb.w;
    f[13] = sc.x - tc.x; f[14] = sc.y - tc.y; f[15] = sc.z - tc.z; f[16] = sc.w - tc.w;
    f[17] = sd.x - td.x; f[18] = sd.y - td.y; f[19] = sd.z - td.z; f[20] = sd.w - td.w;
    f[21] = 1.f;
    unsigned p[16];
#pragma unroll
    for (int j = 0; j < 11; j++) p[j] = pk(f[2 * j], f[2 * j + 1]);
#pragma unroll
    for (int j = 11; j < 16; j++) p[j] = 0u;
#pragma unroll
    for (int g = 0; g < 4; g++) {
        int byte = l * 64 + ((g ^ (l & 3)) << 4);
        u4 w; w.x = p[4 * g]; w.y = p[4 * g + 1]; w.z = p[4 * g + 2]; w.w = p[4 * g + 3];
        *(u4*)(lds + byte) = w;
    }
    __syncthreads();

    u4 B1[4];
#pragma unroll
    for (int n = 0; n < 4; n++) {
        int e = n * 16 + (l & 15);
        int byte = e * 64 + ((((l >> 4) & 3) ^ (e & 3)) << 4);
        B1[n] = *(const u4*)(lds + byte);
    }
    __syncthreads();

    f4 acc[4][4];
#pragma unroll
    for (int m = 0; m < 4; m++)
#pragma unroll
        for (int n = 0; n < 4; n++) { acc[m][n].x = 0.f; acc[m][n].y = 0.f; acc[m][n].z = 0.f; acc[m][n].w = 0.f; }

    const unsigned short* W1u = (const unsigned short*)W1b;
    const unsigned short* W2u = (const unsigned short*)W2b;
    const unsigned short* W3u = (const unsigned short*)W3b;
#pragma unroll
    for (int m = 0; m < 4; m++) {
        u4 w = *(const u4*)(W1u + (m * 16 + (l & 15)) * 32 + (l >> 4) * 8);
#pragma unroll
        for (int n = 0; n < 4; n++) MFMA(acc[m][n], w, B1[n]);
    }
    write_tiles(lds, l, acc, nullptr);
    __syncthreads();

    u4 B2[4][2];
#pragma unroll
    for (int n = 0; n < 4; n++)
#pragma unroll
        for (int ks = 0; ks < 2; ks++) {
            int e = n * 16 + (l & 15);
            int g = ks * 4 + (l >> 4);
            B2[n][ks] = *(const u4*)(lds + e * 128 + ((g ^ (e & 7)) << 4));
        }
    __syncthreads();
#pragma unroll
    for (int m = 0; m < 4; m++)
#pragma unroll
        for (int n = 0; n < 4; n++) { acc[m][n].x = 0.f; acc[m][n].y = 0.f; acc[m][n].z = 0.f; acc[m][n].w = 0.f; }
#pragma unroll
    for (int m = 0; m < 4; m++)
#pragma unroll
        for (int ks = 0; ks < 2; ks++) {
            u4 w = *(const u4*)(W2u + (m * 16 + (l & 15)) * 64 + ks * 32 + (l >> 4) * 8);
#pragma unroll
            for (int n = 0; n < 4; n++) MFMA(acc[m][n], w, B2[n][ks]);
        }
    write_tiles(lds, l, acc, mb2);
    __syncthreads();

#pragma unroll
    for (int n = 0; n < 4; n++)
#pragma unroll
        for (int ks = 0; ks < 2; ks++) {
            int e = n * 16 + (l & 15);
            int g = ks * 4 + (l >> 4);
            B2[n][ks] = *(const u4*)(lds + e * 128 + ((g ^ (e & 7)) << 4));
        }
    __syncthreads();
#pragma unroll
    for (int m = 0; m < 4; m++)
#pragma unroll
        for (int n = 0; n < 4; n++) { acc[m][n].x = 0.f; acc[m][n].y = 0.f; acc[m][n].z = 0.f; acc[m][n].w = 0.f; }
#pragma unroll
    for (int m = 0; m < 4; m++)
#pragma unroll
        for (int ks = 0; ks < 2; ks++) {
            u4 w = *(const u4*)(W3u + (m * 16 + (l & 15)) * 64 + ks * 32 + (l >> 4) * 8);
#pragma unroll
            for (int n = 0; n < 4; n++) MFMA(acc[m][n], w, B2[n][ks]);
        }
    write_tiles(lds, l, acc, mb3);
    __syncthreads();

#pragma unroll
    for (int it = 0; it < 8; it++) {
        int e = it * 8 + (l >> 3);
        int g = l & 7;
        u4 vv = *(const u4*)(lds + e * 128 + ((g ^ (e & 7)) << 4));
        *(u4*)((unsigned short*)msg + (size_t)(e0 + e) * 64 + g * 8) = vv;
    }
}

// ---------------------------------------------------------------- attention aggregate
// wave = node; 4 edge-groups of 16 lanes; lane handles 4 channels per head.
__global__ __launch_bounds__(256) void k_attn(
    const int* __restrict__ row_off, const int* __restrict__ src,
    const __hip_bfloat16* __restrict__ msg,
    const float* __restrict__ qf, const __hip_bfloat16* __restrict__ kvf,
    const float* __restrict__ qwe, const float* __restrict__ selff, const float* __restrict__ skipf,
    const float* __restrict__ we,
    float* __restrict__ outb)
{
    __shared__ float red[4][4][64];
    int tid = threadIdx.x, wid = tid >> 6, lane = tid & 63;
    int g = lane >> 4, c16 = lane & 15;
    int n = blockIdx.x * 4 + wid;

    const f4* q4 = (const f4*)(qf + n * 128);
    f4 q0 = q4[c16], q1 = q4[16 + c16];
    f4 qm0 = *(const f4*)(qwe + n * 168 + 4 * c16);
    f4 qm1 = *(const f4*)(qwe + n * 168 + 84 + 4 * c16);

    float a00 = 0.f, a01 = 0.f;
#pragma unroll
    for (int j = 0; j < 20; j++) {
        float sfj = selff[n * 20 + j];
        a00 += sfj * qwe[n * 168 + 64 + j];
        a01 += sfj * qwe[n * 168 + 84 + 64 + j];
    }

    const unsigned short* msgu = (const unsigned short*)msg;
    const unsigned short* kvu  = (const unsigned short*)kvf;
    int r0 = row_off[n], r1 = row_off[n + 1];
    int nit = (r1 - r0 + 3) >> 2;

    f4 Wv0 = {0,0,0,0}, Wv1 = {0,0,0,0}, Wm0 = {0,0,0,0}, Wm1 = {0,0,0,0};
    float S0 = 0.f, S1 = 0.f;

#pragma unroll 2
    for (int it = 0; it < nit; it++) {
        int e = r0 + it * 4 + g;
        bool ok = (e < r1);
        int ec = ok ? e : r0;
        int s = src[ec];
        const unsigned short* kvp = kvu + (size_t)s * 256 + 4 * c16;
        f4 k0 = bf2f4(*(const ushort4*)(kvp));
        f4 k1 = bf2f4(*(const ushort4*)(kvp + 64));
        f4 v0 = bf2f4(*(const ushort4*)(kvp + 128));
        f4 v1 = bf2f4(*(const ushort4*)(kvp + 192));
        f4 mc = bf2f4(*(const ushort4*)(msgu + (size_t)ec * 64 + 4 * c16));

        float t0 = dot4(q0, k0) + dot4(qm0, mc);
        float t1 = dot4(q1, k1) + dot4(qm1, mc);
#pragma unroll
        for (int mk = 1; mk < 16; mk <<= 1) {
            t0 += __shfl_xor(t0, mk, 64);
            t1 += __shfl_xor(t1, mk, 64);
        }
        float w0 = ok ? __expf((t0 + a00) * 0.125f) : 0.f;
        float w1 = ok ? __expf((t1 + a01) * 0.125f) : 0.f;
        S0 += w0; S1 += w1;
        fma4(Wv0, w0, v0); fma4(Wv1, w1, v1);
        fma4(Wm0, w0, mc); fma4(Wm1, w1, mc);
    }

#pragma unroll
    for (int mk = 16; mk <= 32; mk <<= 1) {
        Wv0.x += __shfl_xor(Wv0.x, mk, 64); Wv0.y += __shfl_xor(Wv0.y, mk, 64);
        Wv0.z += __shfl_xor(Wv0.z, mk, 64); Wv0.w += __shfl_xor(Wv0.w, mk, 64);
        Wv1.x += __shfl_xor(Wv1.x, mk, 64); Wv1.y += __shfl_xor(Wv1.y, mk, 64);
        Wv1.z += __shfl_xor(Wv1.z, mk, 64); Wv1.w += __shfl_xor(Wv1.w, mk, 64);
        Wm0.x += __shfl_xor(Wm0.x, mk, 64); Wm0.y += __shfl_xor(Wm0.y, mk, 64);
        Wm0.z += __shfl_xor(Wm0.z, mk, 64); Wm0.w += __shfl_xor(Wm0.w, mk, 64);
        Wm1.x += __shfl_xor(Wm1.x, mk, 64); Wm1.y += __shfl_xor(Wm1.y, mk, 64);
        Wm1.z += __shfl_xor(Wm1.z, mk, 64); Wm1.w += __shfl_xor(Wm1.w, mk, 64);
        S0 += __shfl_xor(S0, mk, 64); S1 += __shfl_xor(S1, mk, 64);
    }

    if (g == 0) {
        *(f4*)(&red[wid][0][4 * c16]) = Wv0;
        *(f4*)(&red[wid][1][4 * c16]) = Wv1;
        *(f4*)(&red[wid][2][4 * c16]) = Wm0;
        *(f4*)(&red[wid][3][4 * c16]) = Wm1;
    }

    const float* wmA = &red[wid][2][0];
    const float* wmB = &red[wid][3][0];
    float acc0 = 0.f, acc1 = 0.f;
#pragma unroll 4
    for (int a = 0; a < 64; a += 2) {
        acc0 += wmA[a] * we[a * 128 + lane]      + wmA[a + 1] * we[(a + 1) * 128 + lane];
        acc1 += wmB[a] * we[a * 128 + 64 + lane] + wmB[a + 1] * we[(a + 1) * 128 + 64 + lane];
    }
#pragma unroll
    for (int j = 0; j < 20; j++) {
        float sfj = selff[n * 20 + j];
        acc0 += S0 * sfj * we[(64 + j) * 128 + lane];
        acc1 += S1 * sfj * we[(64 + j) * 128 + 64 + lane];
    }
    float o0 = (red[wid][0][lane] + acc0) / (S0 + 1e-16f);
    float o1 = (red[wid][1][lane] + acc1) / (S1 + 1e-16f);
    outb[n * 64 + lane] = 0.5f * (o0 + o1) + skipf[n * 64 + lane];
}

// ---------------------------------------------------------------- final MLP via MFMA (1 wave = 64 nodes)
__global__ __launch_bounds__(64) void k_final_mfma(
    const float* __restrict__ outb,
    const __hip_bfloat16* __restrict__ H1b, const __hip_bfloat16* __restrict__ H2b,
    const __hip_bfloat16* __restrict__ H3b,
    const float* __restrict__ hb1, const float* __restrict__ hb2, const float* __restrict__ hb3,
    float* __restrict__ out)
{
    __shared__ char lds[64 * 128];
    int l = threadIdx.x;
    int n0 = blockIdx.x * 64;
    int nl = n0 + l;
    int nn = (nl < NN) ? nl : (NN - 1);

    const float* row = outb + (size_t)nn * 64;
#pragma unroll
    for (int g = 0; g < 8; g++) {
        u4 w;
        w.x = pk(row[8 * g + 0], row[8 * g + 1]);
        w.y = pk(row[8 * g + 2], row[8 * g + 3]);
        w.z = pk(row[8 * g + 4], row[8 * g + 5]);
        w.w = pk(row[8 * g + 6], row[8 * g + 7]);
        *(u4*)(lds + l * 128 + ((g ^ (l & 7)) << 4)) = w;
    }
    __syncthreads();

    const unsigned short* H1u = (const unsigned short*)H1b;
    const unsigned short* H2u = (const unsigned short*)H2b;
    const unsigned short* H3u = (const unsigned short*)H3b;

    u4 B[4][2];
    f4 acc[4][4];

    // ---- stage 1
#pragma unroll
    for (int n = 0; n < 4; n++)
#pragma unroll
        for (int ks = 0; ks < 2; ks++) {
            int e = n * 16 + (l & 15);
            int g = ks * 4 + (l >> 4);
            B[n][ks] = *(const u4*)(lds + e * 128 + ((g ^ (e & 7)) << 4));
        }
    __syncthreads();
#pragma unroll
    for (int m = 0; m < 4; m++)
#pragma unroll
        for (int n = 0; n < 4; n++) { acc[m][n].x = 0.f; acc[m][n].y = 0.f; acc[m][n].z = 0.f; acc[m][n].w = 0.f; }
#pragma unroll
    for (int m = 0; m < 4; m++)
#pragma unroll
        for (int ks = 0; ks < 2; ks++) {
            u4 w = *(const u4*)(H1u + (m * 16 + (l & 15)) * 64 + ks * 32 + (l >> 4) * 8);
#pragma unroll
            for (int n = 0; n < 4; n++) MFMA(acc[m][n], w, B[n][ks]);
        }
    write_tiles(lds, l, acc, hb1);
    __syncthreads();

    // ---- stage 2
#pragma unroll
    for (int n = 0; n < 4; n++)
#pragma unroll
        for (int ks = 0; ks < 2; ks++) {
            int e = n * 16 + (l & 15);
            int g = ks * 4 + (l >> 4);
            B[n][ks] = *(const u4*)(lds + e * 128 + ((g ^ (e & 7)) << 4));
        }
    __syncthreads();
#pragma unroll
    for (int m = 0; m < 4; m++)
#pragma unroll
        for (int n = 0; n < 4; n++) { acc[m][n].x = 0.f; acc[m][n].y = 0.f; acc[m][n].z = 0.f; acc[m][n].w = 0.f; }
#pragma unroll
    for (int m = 0; m < 4; m++)
#pragma unroll
        for (int ks = 0; ks < 2; ks++) {
            u4 w = *(const u4*)(H2u + (m * 16 + (l & 15)) * 64 + ks * 32 + (l >> 4) * 8);
#pragma unroll
            for (int n = 0; n < 4; n++) MFMA(acc[m][n], w, B[n][ks]);
        }
    write_tiles(lds, l, acc, hb2);
    __syncthreads();

    // ---- stage 3: 64 -> 20
#pragma unroll
    for (int n = 0; n < 4; n++)
#pragma unroll
        for (int ks = 0; ks < 2; ks++) {
            int e = n * 16 + (l & 15);
            int g = ks * 4 + (l >> 4);
            B[n][ks] = *(const u4*)(lds + e * 128 + ((g ^ (e & 7)) << 4));
        }

    f4 acc3[2][4];
#pragma unroll
    for (int m = 0; m < 2; m++)
#pragma unroll
        for (int n = 0; n < 4; n++) { acc3[m][n].x = 0.f; acc3[m][n].y = 0.f; acc3[m][n].z = 0.f; acc3[m][n].w = 0.f; }
#pragma unroll
    for (int m = 0; m < 2; m++)
#pragma unroll
        for (int ks = 0; ks < 2; ks++) {
            u4 w = *(const u4*)(H3u + (m * 16 + (l & 15)) * 64 + ks * 32 + (l >> 4) * 8);
#pragma unroll
            for (int n = 0; n < 4; n++) MFMA(acc3[m][n], w, B[n][ks]);
        }

#pragma unroll
    for (int m = 0; m < 2; m++) {
#pragma unroll
        for (int j = 0; j < 4; j++) {
            int ch = m * 16 + (l >> 4) * 4 + j;
            if (ch < 20) {
                float b = hb3[ch];
#pragma unroll
                for (int nt = 0; nt < 4; nt++) {
                    int node = n0 + nt * 16 + (l & 15);
                    if (node < NN) {
                        float v = acc3[m][nt][j] + b;
                        if (ch < 2)       out[node * 2 + ch] = v;
                        else if (ch == 2) out[2 * NN + node] = v;
                        else if (ch < 19) out[3 * NN + node * 16 + (ch - 3)] = v;
                        else              out[19 * NN + node] = v;
                    }
                }
            }
        }
    }
}

// ---------------------------------------------------------------- launch
extern "C" void kernel_launch(void* const* d_in, const int* in_sizes, int n_in,
                              void* d_out, int out_size, void* d_ws, size_t ws_size,
                              hipStream_t stream)
{
    const float* x      = (const float*)d_in[0];
    const float* angle  = (const float*)d_in[1];
    const float* mol    = (const float*)d_in[2];
    const float* gen    = (const float*)d_in[3];
    const int*   src    = (const int*)d_in[4];
    const int*   dst    = (const int*)d_in[5];
    const float* mask   = (const float*)d_in[6];
    const float* mw1    = (const float*)d_in[7];
    const float* mb1    = (const float*)d_in[8];
    const float* mw2    = (const float*)d_in[9];
    const float* mb2    = (const float*)d_in[10];
    const float* mw3    = (const float*)d_in[11];
    const float* mb3    = (const float*)d_in[12];
    const float* wq     = (const float*)d_in[13];
    const float* bq     = (const float*)d_in[14];
    const float* wk     = (const float*)d_in[15];
    const float* bk     = (const float*)d_in[16];
    const float* wv     = (const float*)d_in[17];
    const float* bv     = (const float*)d_in[18];
    const float* we     = (const float*)d_in[19];
    const float* wskip  = (const float*)d_in[20];
    const float* bskip  = (const float*)d_in[21];
    const float* hw1    = (const float*)d_in[22];
    const float* hb1    = (const float*)d_in[23];
    const float* hw2    = (const float*)d_in[24];
    const float* hb2    = (const float*)d_in[25];
    const float* hw3    = (const float*)d_in[26];
    const float* hb3    = (const float*)d_in[27];
    float* out = (float*)d_out;

    char* p = (char*)d_ws;
    auto alloc = [&](size_t bytes) -> void* {
        void* r = (void*)p;
        p += (bytes + 255) & ~(size_t)255;
        return r;
    };
    int*   row_off = (int*)alloc((NN + 1) * 4);
    float* selff   = (float*)alloc((size_t)NN * 20 * 4);
    float* qf      = (float*)alloc((size_t)NN * 128 * 4);
    __hip_bfloat16* kvf = (__hip_bfloat16*)alloc((size_t)NN * 256 * 2);
    float* skipf   = (float*)alloc((size_t)NN * 64 * 4);
    float* qwe     = (float*)alloc((size_t)NN * 168 * 4);
    float* outb    = (float*)alloc((size_t)NN * 64 * 4);
    __hip_bfloat16* W1b = (__hip_bfloat16*)alloc(2048 * 2);
    __hip_bfloat16* W2b = (__hip_bfloat16*)alloc(4096 * 2);
    __hip_bfloat16* W3b = (__hip_bfloat16*)alloc(4096 * 2);
    __hip_bfloat16* H1b = (__hip_bfloat16*)alloc(4096 * 2);
    __hip_bfloat16* H2b = (__hip_bfloat16*)alloc(4096 * 2);
    __hip_bfloat16* H3b = (__hip_bfloat16*)alloc(2048 * 2);
    float* weT     = (float*)alloc(10752 * 4);
    __hip_bfloat16* msg = (__hip_bfloat16*)alloc((size_t)EF * 64 * 2);

    k_prep<<<123, 256, 0, stream>>>(mw1, mb1, mw2, mw3, hw1, hw2, hw3, we,
                                    W1b, W2b, W3b, H1b, H2b, H3b, weT);
    k_csr<<<(NN + 256) / 256, 256, 0, stream>>>(dst, mask, row_off);
    k_node<<<NN / 4, 256, 0, stream>>>(angle, mol, gen, row_off, wq, bq, wk, bk, wv, bv,
                                       wskip, bskip, weT, selff, qf, kvf, skipf, qwe);
    k_edge_mfma<<<(EF / 64 + 3) / 4, 256, 0, stream>>>(x, angle, mol, src, dst,
                                                       W1b, W2b, W3b, mb2, mb3, msg);
    k_attn<<<NN / 4, 256, 0, stream>>>(row_off, src, msg, qf, kvf,
                                       qwe, selff, skipf, we, outb);
    k_final_mfma<<<(NN + 63) / 64, 64, 0, stream>>>(outb, H1b, H2b, H3b, hb1, hb2, hb3, out);
}